// Round 7
// baseline (1707.829 us; speedup 1.0000x reference)
//
#include <hip/hip_runtime.h>
#include <cfloat>

// N=50000, C=128, H=4, HC=512, E=600000, T=3, Et=200000
// GAT(2x3) -> biLSTM JK -> pool -> MLP. GEMMs in bf16 MFMA (fp32 accum).
// R7: lstm_all redesigned to FIT the 128-VGPR budget by construction:
// 64-row blocks (acc[4]+creg[4][4] = 32 regs vs 64), 8 waves = 4 row-strips
// x 2 col-halves, LDS 48KB (A 16K + H dbuf 32K) -> 2 blocks/CU, no spill.

typedef __attribute__((ext_vector_type(8))) short short8;
typedef __attribute__((ext_vector_type(4))) float f32x4;

#define DEG_CAP 32   // P(Poisson(4) >= 32) ~ 1e-18

__device__ __forceinline__ float lrelu(float x, float s) { return x > 0.f ? x : s * x; }

__device__ __forceinline__ float sigmf(float x) {
    return __builtin_amdgcn_rcpf(1.f + __expf(-x));
}
__device__ __forceinline__ float tanhf_fast(float x) {
    x = fminf(fmaxf(x, -15.f), 15.f);
    float e = __expf(2.f * x);
    return (e - 1.f) * __builtin_amdgcn_rcpf(e + 1.f);
}

__device__ __forceinline__ unsigned f2bf(float f) {   // RNE f32->bf16 (bits)
    unsigned u = __float_as_uint(f);
    return (u + 0x7FFFu + ((u >> 16) & 1u)) >> 16;
}

// bijective XCD-chunked swizzle (m204): consecutive tiles land on one XCD
__device__ __forceinline__ int xcd_tile(int bid, int nwg) {
    int q = nwg >> 3, r = nwg & 7;
    int xcd = bid & 7, idx = bid >> 3;
    return (xcd < r ? xcd * (q + 1) : r * (q + 1) + (xcd - r) * q) + idx;
}

// stage 128x128 A (f32->bf16, XOR-swizzled) + 128x128 B (bf16) into LDS. 512 thr.
__device__ __forceinline__ void stage_tiles(
    char* ldsA, char* ldsB, const float* __restrict__ A,
    const ushort* __restrict__ Bt, int row0, int col0, int M, int tid)
{
#pragma unroll
    for (int it = 0; it < 4; ++it) {
        int idx = it * 512 + tid;
        int r = idx >> 4, kc = (idx & 15) << 3;
        int row = row0 + r;
        float4 v0 = make_float4(0.f, 0.f, 0.f, 0.f), v1 = v0;
        if (row < M) {
            const float* ap = A + (long)row * 128 + kc;
            v0 = *(const float4*)ap;
            v1 = *(const float4*)(ap + 4);
        }
        uint4 w;
        w.x = f2bf(v0.x) | (f2bf(v0.y) << 16);
        w.y = f2bf(v0.z) | (f2bf(v0.w) << 16);
        w.z = f2bf(v1.x) | (f2bf(v1.y) << 16);
        w.w = f2bf(v1.z) | (f2bf(v1.w) << 16);
        int off = (r * 256 + kc * 2) ^ ((r & 7) << 4);
        *(uint4*)(ldsA + off) = w;
        *(uint4*)(ldsB + off) = *(const uint4*)(Bt + (long)(col0 + r) * 128 + kc);
    }
}

// per-wave 32x64 MFMA tile compute (8 waves cover 128x128)
__device__ __forceinline__ void compute_tile(
    const char* ldsA, const char* ldsB, f32x4 acc[2][4],
    int wr, int wc, int lr, int lk)
{
#pragma unroll
    for (int ks = 0; ks < 4; ++ks) {
        int kb = ks * 64 + lk;
        short8 af[2], bfr[4];
#pragma unroll
        for (int i = 0; i < 2; ++i) {
            int r = wr + i * 16 + lr;
            af[i] = *(const short8*)(ldsA + ((r * 256 + kb) ^ ((r & 7) << 4)));
        }
#pragma unroll
        for (int j = 0; j < 4; ++j) {
            int c = wc + j * 16 + lr;
            bfr[j] = *(const short8*)(ldsB + ((c * 256 + kb) ^ ((c & 7) << 4)));
        }
#pragma unroll
        for (int i = 0; i < 2; ++i)
#pragma unroll
            for (int j = 0; j < 4; ++j)
                acc[i][j] = __builtin_amdgcn_mfma_f32_16x16x32_bf16(af[i], bfr[j], acc[i][j], 0, 0, 0);
    }
}

// ---------------- GAT GEMM: xp[M,512] = A @ Bt^T ; fused als/ald (att dots)
__global__ __launch_bounds__(512, 4) void gemm_att(
    const float* __restrict__ A, const ushort* __restrict__ Bt,
    float* __restrict__ C, const float* __restrict__ a_s,
    const float* __restrict__ a_d, float* __restrict__ als,
    float* __restrict__ ald, int M, int nwg)
{
    __shared__ char lds[65536];
    __shared__ float smS[128], smD[128];
    char* ldsA = lds;
    char* ldsB = lds + 32768;
    const int tid = threadIdx.x;
    int tile = xcd_tile(blockIdx.x, nwg);
    int row0 = (tile >> 2) * 128;
    int h = tile & 3;                 // col tile == head
    int col0 = h * 128;
    if (tid < 128) { smS[tid] = 0.f; smD[tid] = 0.f; }
    stage_tiles(ldsA, ldsB, A, Bt, row0, col0, M, tid);
    __syncthreads();

    const int wv = tid >> 6, lane = tid & 63;
    const int wr = (wv & 3) * 32, wc = (wv >> 2) * 64;
    const int lr = lane & 15;
    const int lk = (lane >> 4) << 4;
    f32x4 acc[2][4] = {};
    compute_tile(ldsA, ldsB, acc, wr, wc, lr, lk);

    const float* asl = a_s + h * 128;
    const float* adl = a_d + h * 128;
#pragma unroll
    for (int i = 0; i < 2; ++i) {
#pragma unroll
        for (int q = 0; q < 4; ++q) {
            float ps = 0.f, pd = 0.f;
            int row = row0 + wr + i * 16 + (lane >> 4) * 4 + q;
#pragma unroll
            for (int j = 0; j < 4; ++j) {
                int cc = wc + j * 16 + lr;
                float v = acc[i][j][q];
                ps += v * asl[cc];
                pd += v * adl[cc];
                if (row < M) C[(long)row * 512 + col0 + cc] = v;
            }
#pragma unroll
            for (int off = 8; off; off >>= 1) {
                ps += __shfl_xor(ps, off);
                pd += __shfl_xor(pd, off);
            }
            if (lr == 0) {
                int rl = wr + i * 16 + (lane >> 4) * 4 + q;
                atomicAdd(&smS[rl], ps);
                atomicAdd(&smD[rl], pd);
            }
        }
    }
    __syncthreads();
    if (tid < 128) {
        int row = row0 + tid;
        if (row < M) {
            als[(long)row * 4 + h] = smS[tid];
            ald[(long)row * 4 + h] = smD[tid];
        }
    }
}

// ---------------- persistent biLSTM + JK scores. Grid (RB64, 2): y = direction.
// xb: [3][N][128] bf16 (x,l1,l2). lwt: [4][512][128] bf16, gate-interleaved:
// col' = (ch>>4)*64 + gate*16 + (ch&15). Block owns 64 rows for its 3 steps.
// 8 waves = 4 x 16-row strips x 2 col-halves. Per-thread: acc[4] + creg[4][4]
// = 32 regs -> fits the 128-VGPR budget, no scratch. c in regs, h in LDS
// (2x16KB dbuf), A in 16KB LDS panel, B streamed from global (L2-resident).
__global__ __launch_bounds__(512, 2) void lstm_all(
    const ushort* __restrict__ xb, const ushort* __restrict__ lwt,
    const float* __restrict__ bihf, const float* __restrict__ bhhf,
    const float* __restrict__ bihb, const float* __restrict__ bhhb,
    const float* __restrict__ jkw, float* __restrict__ score, int N)
{
    __shared__ ushort ldsH[2][8192];    // 2 x 64 rows x 128 ch bf16, XOR-swz
    __shared__ ushort ldsA[8192];       // A panel, same layout
    __shared__ float ssc[64];
    const int tid = threadIdx.x;
    const int row0 = blockIdx.x * 64;
    const int dir = blockIdx.y;
    const int wv = tid >> 6, lane = tid & 63;
    const int wr = (wv & 3) * 16;      // 16-row strip
    const int wc64 = wv >> 2;          // col half (0/1) within each 128 chunk
    const int lr = lane & 15, lg = lane >> 4;

    const ushort* Bih = lwt + (long)(dir ? 2 : 0) * 65536;
    const ushort* Bhh = lwt + (long)(dir ? 3 : 1) * 65536;
    const float* bi = dir ? bihb : bihf;
    const float* bh = dir ? bhhb : bhhf;
    const float* jw = jkw + (dir ? 128 : 0);
    float bI[4], bF[4], bG[4], bO[4], jv[4];
#pragma unroll
    for (int cc = 0; cc < 4; ++cc) {
        int ch = (cc * 2 + wc64) * 16 + lr;
        bI[cc] = bi[ch] + bh[ch];
        bF[cc] = bi[128 + ch] + bh[128 + ch];
        bG[cc] = bi[256 + ch] + bh[256 + ch];
        bO[cc] = bi[384 + ch] + bh[384 + ch];
        jv[cc] = jw[ch];
    }
    float creg[4][4];
#pragma unroll
    for (int cc = 0; cc < 4; ++cc)
#pragma unroll
        for (int q = 0; q < 4; ++q) creg[cc][q] = 0.f;

    for (int j = 0; j < 3; ++j) {
        int l = dir ? (2 - j) : j;
        const ushort* Ab = xb + (long)l * N * 128;
        const ushort* Hprev = ldsH[(j + 1) & 1];
        ushort* Hcur = ldsH[j & 1];
        if (tid < 64) ssc[tid] = 0.f;
        // stage A panel: 64 rows x 128 ch bf16 (tid-linear, coalesced)
#pragma unroll
        for (int it = 0; it < 2; ++it) {
            int idx = it * 512 + tid;
            int r = idx >> 4, kc = (idx & 15) << 3;
            int row = row0 + r;
            uint4 v = make_uint4(0, 0, 0, 0);
            if (row < N) v = *(const uint4*)(Ab + (long)row * 128 + kc);
            *(uint4*)((char*)ldsA + ((r * 256 + kc * 2) ^ ((r & 7) << 4))) = v;
        }
        __syncthreads();     // A staged; prev-step Hcur writes + ssc zero visible

        float psum[4] = {0.f, 0.f, 0.f, 0.f};

#pragma unroll
        for (int cc = 0; cc < 4; ++cc) {
            f32x4 acc[4] = {};
            // ---- ih GEMM: A fragments from LDS panel
#pragma unroll
            for (int ks = 0; ks < 4; ++ks) {
                int rl = wr + lr;
                short8 af = *(const short8*)((const char*)ldsA +
                             ((rl * 256 + ks * 64 + lg * 16) ^ ((rl & 7) << 4)));
#pragma unroll
                for (int g = 0; g < 4; ++g) {
                    int cp = cc * 128 + wc64 * 64 + g * 16 + lr;
                    short8 bv = *(const short8*)(Bih + (long)cp * 128 + ks * 32 + lg * 8);
                    acc[g] = __builtin_amdgcn_mfma_f32_16x16x32_bf16(af, bv, acc[g], 0, 0, 0);
                }
            }
            // ---- hh GEMM: h fragments from LDS (prev buf)
            if (j > 0) {
#pragma unroll
                for (int ks = 0; ks < 4; ++ks) {
                    int rl = wr + lr;
                    short8 ah = *(const short8*)((const char*)Hprev +
                                 ((rl * 256 + ks * 64 + lg * 16) ^ ((rl & 7) << 4)));
#pragma unroll
                    for (int g = 0; g < 4; ++g) {
                        int cp = cc * 128 + wc64 * 64 + g * 16 + lr;
                        short8 bv = *(const short8*)(Bhh + (long)cp * 128 + ks * 32 + lg * 8);
                        acc[g] = __builtin_amdgcn_mfma_f32_16x16x32_bf16(ah, bv, acc[g], 0, 0, 0);
                    }
                }
            }
            // ---- cell pointwise: acc[gate][q], gate order i,f,g,o
            int ch = (cc * 2 + wc64) * 16 + lr;
#pragma unroll
            for (int q = 0; q < 4; ++q) {
                float cv = sigmf(acc[1][q] + bF[cc]) * creg[cc][q]
                         + sigmf(acc[0][q] + bI[cc]) * tanhf_fast(acc[2][q] + bG[cc]);
                float hv = sigmf(acc[3][q] + bO[cc]) * tanhf_fast(cv);
                creg[cc][q] = cv;
                psum[q] += hv * jv[cc];
                int rl = wr + lg * 4 + q;
                *(ushort*)((char*)Hcur + ((rl * 256 + ch * 2) ^ ((rl & 7) << 4))) =
                    (ushort)f2bf(hv);
            }
        }
        // JK score partial: reduce over lr (16 lanes); cc folded in psum
#pragma unroll
        for (int q = 0; q < 4; ++q) {
            float p = psum[q];
#pragma unroll
            for (int off = 8; off; off >>= 1) p += __shfl_xor(p, off);
            if (lr == 0)
                atomicAdd(&ssc[wr + lg * 4 + q], p);
        }
        __syncthreads();     // Hcur + ssc complete before next step / score
        if (tid < 64) {
            int row = row0 + tid;
            if (row < N) unsafeAtomicAdd(&score[(long)l * N + row], ssc[tid]);
        }
    }
}

// ---------------- weight prepack
__global__ void pack_gatw(const float* __restrict__ gw, ushort* __restrict__ out) {
    int i = blockIdx.x * 256 + threadIdx.x;
    if (i >= 6 * 65536) return;
    int pt = i >> 16, rem = i & 65535, n = rem >> 7, k = rem & 127;
    out[i] = (ushort)f2bf(gw[pt * 65536 + k * 512 + n]);
}
// LSTM weights, gate-interleaved permutation: col' -> orig row g*128+ch
__global__ void pack_lstm(const float* __restrict__ a, const float* __restrict__ b,
                          const float* __restrict__ c, const float* __restrict__ d,
                          ushort* __restrict__ out) {
    int i = blockIdx.x * 256 + threadIdx.x;
    if (i >= 4 * 65536) return;
    const float* p = (i < 65536) ? a : (i < 131072) ? b : (i < 196608) ? c : d;
    int rem = i & 65535;
    int cp = rem >> 7, k = rem & 127;
    int g = (cp >> 4) & 3;
    int ch = ((cp >> 6) << 4) | (cp & 15);
    out[i] = (ushort)f2bf(p[(g * 128 + ch) * 128 + k]);
}
// x f32 -> bf16
__global__ void pack_x(const float* __restrict__ x, ushort* __restrict__ o, long n) {
    long i = ((long)blockIdx.x * 256 + threadIdx.x) * 4;
    if (i >= n) return;
    float4 v = *(const float4*)(x + i);
    ushort4 u;
    u.x = (ushort)f2bf(v.x); u.y = (ushort)f2bf(v.y);
    u.z = (ushort)f2bf(v.z); u.w = (ushort)f2bf(v.w);
    *(ushort4*)(o + i) = u;
}

// ---------------- CSR build: bucket incoming edges by dst (per edge type)
__global__ __launch_bounds__(256) void build_csr(
    const int* __restrict__ srcs, const int* __restrict__ dsts,
    int E, int Et, int N, int* __restrict__ cnt, int* __restrict__ bucket)
{
    int i = blockIdx.x * 256 + threadIdx.x;
    if (i >= E) return;
    int t = i / Et;
    int s = srcs[i];
    int d = dsts[i];
    int slot = atomicAdd(&cnt[t * N + d], 1);
    if (slot < DEG_CAP) bucket[((long)(t * N + d)) * DEG_CAP + slot] = s;
}

// ---------------- fused GAT aggregation: one wave per dst node, depth-2 SW pipe
// dst += (or =) lrelu(msg+bias)/3; on final t also writes bf16 copy for LSTM.
__global__ __launch_bounds__(256) void gat_gather(
    const int* __restrict__ cnt, const int* __restrict__ bucket,
    const float* __restrict__ als, const float* __restrict__ ald,
    const float* __restrict__ xp, const float* __restrict__ bias,
    float* __restrict__ dstb, ushort* __restrict__ out16, int N, int t, int first)
{
    int d = blockIdx.x * 4 + (threadIdx.x >> 6);
    int lane = threadIdx.x & 63;
    if (d >= N) return;
    int deg = min(cnt[t * N + d], DEG_CAP);
    int s = d;
    if (lane < deg) s = bucket[((long)(t * N + d)) * DEG_CAP + lane];
    bool act = (lane <= deg);
    float4 ad = *(const float4*)(ald + (long)d * 4);
    float l0 = -FLT_MAX, l1 = -FLT_MAX, l2 = -FLT_MAX, l3 = -FLT_MAX;
    if (act) {
        float4 as = *(const float4*)(als + (long)s * 4);
        l0 = lrelu(as.x + ad.x, 0.2f);
        l1 = lrelu(as.y + ad.y, 0.2f);
        l2 = lrelu(as.z + ad.z, 0.2f);
        l3 = lrelu(as.w + ad.w, 0.2f);
    }
    float m0 = l0, m1 = l1, m2 = l2, m3 = l3;
#pragma unroll
    for (int off = 32; off; off >>= 1) {
        m0 = fmaxf(m0, __shfl_xor(m0, off));
        m1 = fmaxf(m1, __shfl_xor(m1, off));
        m2 = fmaxf(m2, __shfl_xor(m2, off));
        m3 = fmaxf(m3, __shfl_xor(m3, off));
    }
    float e0 = 0.f, e1 = 0.f, e2 = 0.f, e3 = 0.f;
    if (act) {
        e0 = __expf(l0 - m0); e1 = __expf(l1 - m1);
        e2 = __expf(l2 - m2); e3 = __expf(l3 - m3);
    }
    float s0 = e0, s1 = e1, s2 = e2, s3 = e3;
#pragma unroll
    for (int off = 32; off; off >>= 1) {
        s0 += __shfl_xor(s0, off);
        s1 += __shfl_xor(s1, off);
        s2 += __shfl_xor(s2, off);
        s3 += __shfl_xor(s3, off);
    }
    float a0 = 0.25f * e0 / s0, a1 = 0.25f * e1 / s1;
    float a2 = 0.25f * e2 / s2, a3 = 0.25f * e3 / s3;

    // depth-2 software pipeline over incoming edges (+self)
    float acc0 = 0.f, acc1 = 0.f;
    int sj = __shfl(s, 0);
    const float* xs = xp + (long)sj * 512;
    float c0 = xs[lane],       c1 = xs[64 + lane];
    float c2 = xs[128 + lane], c3 = xs[192 + lane];
    float c4 = xs[256 + lane], c5 = xs[320 + lane];
    float c6 = xs[384 + lane], c7 = xs[448 + lane];
    for (int j = 0; j < deg; ++j) {
        int sn = __shfl(s, j + 1);
        const float* xn = xp + (long)sn * 512;
        float n0 = xn[lane],       n1 = xn[64 + lane];
        float n2 = xn[128 + lane], n3 = xn[192 + lane];
        float n4 = xn[256 + lane], n5 = xn[320 + lane];
        float n6 = xn[384 + lane], n7 = xn[448 + lane];
        float w0 = __shfl(a0, j), w1 = __shfl(a1, j);
        float w2 = __shfl(a2, j), w3 = __shfl(a3, j);
        acc0 += w0 * c0 + w1 * c2 + w2 * c4 + w3 * c6;
        acc1 += w0 * c1 + w1 * c3 + w2 * c5 + w3 * c7;
        c0 = n0; c1 = n1; c2 = n2; c3 = n3;
        c4 = n4; c5 = n5; c6 = n6; c7 = n7;
    }
    float w0 = __shfl(a0, deg), w1 = __shfl(a1, deg);
    float w2 = __shfl(a2, deg), w3 = __shfl(a3, deg);
    acc0 += w0 * c0 + w1 * c2 + w2 * c4 + w3 * c6;
    acc1 += w0 * c1 + w1 * c3 + w2 * c5 + w3 * c7;

    float r0 = lrelu(acc0 + bias[lane], 0.01f) * (1.f / 3.f);
    float r1 = lrelu(acc1 + bias[lane + 64], 0.01f) * (1.f / 3.f);
    float* ap = dstb + (long)d * 128;
    float f0, f1;
    if (first) { f0 = r0; f1 = r1; }
    else       { f0 = ap[lane] + r0; f1 = ap[lane + 64] + r1; }
    ap[lane] = f0; ap[lane + 64] = f1;
    if (out16) {
        out16[(long)d * 128 + lane]      = (ushort)f2bf(f0);
        out16[(long)d * 128 + 64 + lane] = (ushort)f2bf(f1);
    }
}

__global__ void jk_kernel(const float* __restrict__ score, const float* __restrict__ x0,
                          const float* __restrict__ x1, const float* __restrict__ x2,
                          float* __restrict__ xjk, int N)
{
    long i = (long)blockIdx.x * 256 + threadIdx.x;
    long n = i >> 7;
    if (n >= N) return;
    float s0 = score[n], s1 = score[N + n], s2 = score[2L * N + n];
    float m = fmaxf(s0, fmaxf(s1, s2));
    float e0 = expf(s0 - m), e1 = expf(s1 - m), e2 = expf(s2 - m);
    float inv = 1.f / (e0 + e1 + e2);
    xjk[i] = (e0 * x0[i] + e1 * x1[i] + e2 * x2[i]) * inv;
}

// z0 init: zeros + ptype in col 128
__global__ void init_z0(const float* __restrict__ ptype, float* __restrict__ z0) {
    int i = blockIdx.x * 128 + threadIdx.x;
    if (i < 64 * 129) z0[i] = ((i % 129) == 128) ? ptype[i / 129] : 0.f;
}

// parallel pool: 64-node chunks, flush on graph boundary
__global__ __launch_bounds__(128) void pool2(
    const float* __restrict__ xjk, const int* __restrict__ batch,
    float* __restrict__ z0, int N)
{
    int c = threadIdx.x;
    int n0 = blockIdx.x * 64;
    if (n0 >= N) return;
    int n1 = min(n0 + 64, N);
    float s = 0.f;
    int g = batch[n0];
    for (int n = n0; n < n1; ++n) {
        int b = batch[n];
        if (b != g) { unsafeAtomicAdd(&z0[g * 129 + c], s); s = 0.f; g = b; }
        s += xjk[(long)n * 128 + c];
    }
    unsafeAtomicAdd(&z0[g * 129 + c], s);
}

__global__ __launch_bounds__(128) void mlp_kernel(
    const float* __restrict__ z0, const float* __restrict__ w1, const float* __restrict__ b1,
    const float* __restrict__ w2, const float* __restrict__ b2,
    const float* __restrict__ w3, const float* __restrict__ b3,
    float* __restrict__ out)
{
    int gidx = blockIdx.x, tid = threadIdx.x;
    __shared__ float zin[129], z1[80], z2[80];
    zin[tid] = z0[gidx * 129 + tid];
    if (tid == 0) zin[128] = z0[gidx * 129 + 128];
    __syncthreads();
    if (tid < 80) {
        float s = b1[tid];
        for (int k = 0; k < 129; ++k) s += zin[k] * w1[k * 80 + tid];
        z1[tid] = lrelu(s, 0.01f);
    }
    __syncthreads();
    if (tid < 80) {
        float s = b2[tid];
        for (int k = 0; k < 80; ++k) s += z1[k] * w2[k * 80 + tid];
        z2[tid] = lrelu(s, 0.01f);
    }
    __syncthreads();
    if (tid < 10) {
        float s = b3[tid];
        for (int k = 0; k < 80; ++k) s += z2[k] * w3[k * 10 + tid];
        out[gidx * 10 + tid] = s;
    }
}

extern "C" void kernel_launch(void* const* d_in, const int* in_sizes, int n_in,
                              void* d_out, int out_size, void* d_ws, size_t ws_size,
                              hipStream_t stream)
{
    (void)n_in; (void)out_size; (void)ws_size;
    const float* x      = (const float*)d_in[0];
    const int*   ei     = (const int*)d_in[1];
    const int*   batch  = (const int*)d_in[2];
    const float* ptype  = (const float*)d_in[3];
    const float* gatW   = (const float*)d_in[4];
    const float* gatAs  = (const float*)d_in[5];
    const float* gatAd  = (const float*)d_in[6];
    const float* gatB   = (const float*)d_in[7];
    const float* w_ih_fw = (const float*)d_in[8];
    const float* w_hh_fw = (const float*)d_in[9];
    const float* b_ih_fw = (const float*)d_in[10];
    const float* b_hh_fw = (const float*)d_in[11];
    const float* w_ih_bw = (const float*)d_in[12];
    const float* w_hh_bw = (const float*)d_in[13];
    const float* b_ih_bw = (const float*)d_in[14];
    const float* b_hh_bw = (const float*)d_in[15];
    const float* jkw    = (const float*)d_in[16];
    const float* fc1w   = (const float*)d_in[18];
    const float* fc1b   = (const float*)d_in[19];
    const float* fc2w   = (const float*)d_in[20];
    const float* fc2b   = (const float*)d_in[21];
    const float* fc3w   = (const float*)d_in[22];
    const float* fc3b   = (const float*)d_in[23];

    const int N = in_sizes[0] / 128;
    const int E = in_sizes[1] / 2;
    const int Et = E / 3;
    const long NC = (long)N * 128;

    float* w = (float*)d_ws;
    float* xp   = w; w += (long)N * 512;    // GAT projections
    float* l1   = w; w += NC;
    float* l2   = w; w += NC;
    float* accb = w; w += NC;               // xjk
    float* outm = w; w += NC;               // GAT: CSR cnt+bucket
    ushort* xb16 = (ushort*)w; w += 3L * N * 64;   // [3][N][128] bf16 seq
    float* als  = w; w += (long)N * 4;
    float* ald  = w; w += (long)N * 4;
    float* score = w; w += 3L * N;
    ushort* gwt = (ushort*)w; w += 6 * 65536 / 2;   // bf16 GAT weights [6][512][128]
    ushort* lwt = (ushort*)w; w += 4 * 65536 / 2;   // bf16 LSTM weights (permuted)
    float* z0   = w; w += 64 * 129 + 4;

    // CSR aliases the outm region (GAT phase only)
    int* cnt    = (int*)outm;
    int* bucket = cnt + 3L * N;

    pack_gatw<<<(6 * 65536 + 255) / 256, 256, 0, stream>>>(gatW, gwt);
    pack_lstm<<<(4 * 65536 + 255) / 256, 256, 0, stream>>>(w_ih_fw, w_hh_fw, w_ih_bw, w_hh_bw, lwt);
    pack_x<<<(int)((NC / 4 + 255) / 256), 256, 0, stream>>>(x, xb16, NC);
    hipMemsetAsync(score, 0, sizeof(float) * 3 * N, stream);
    hipMemsetAsync(cnt, 0, sizeof(int) * 3 * N, stream);
    build_csr<<<(E + 255) / 256, 256, 0, stream>>>(ei, ei + E, E, Et, N, cnt, bucket);

    const int RB = (N + 127) / 128;
    const int nwg = RB * 4;
    const int ncb = (int)((NC + 255) / 256);

    // ---- GAT layers
    const float* cur = x;
    for (int p = 0; p < 2; ++p) {
        float* dstb = (p == 0) ? l1 : l2;
        ushort* d16 = xb16 + (long)(p + 1) * N * 128;
        for (int t = 0; t < 3; ++t) {
            int pt = p * 3 + t;
            gemm_att<<<nwg, 512, 0, stream>>>(cur, gwt + (long)pt * 65536, xp,
                                              gatAs + pt * 512, gatAd + pt * 512,
                                              als, ald, N, nwg);
            gat_gather<<<(N + 3) / 4, 256, 0, stream>>>(cnt, bucket, als, ald, xp,
                                                        gatB + pt * 128, dstb,
                                                        (t == 2) ? d16 : nullptr,
                                                        N, t, t == 0);
        }
        cur = dstb;
    }

    // ---- persistent fused bi-LSTM + JK scores (one launch, fw/bw in parallel)
    const int RB64 = (N + 63) / 64;
    lstm_all<<<dim3(RB64, 2), 512, 0, stream>>>(xb16, lwt, b_ih_fw, b_hh_fw,
                                                b_ih_bw, b_hh_bw, jkw, score, N);

    // ---- JK softmax-weighted sum, pool, MLP
    jk_kernel<<<ncb, 256, 0, stream>>>(score, x, l1, l2, accb, N);
    init_z0<<<65, 128, 0, stream>>>(ptype, z0);
    pool2<<<(N + 63) / 64, 128, 0, stream>>>(accb, batch, z0, N);
    mlp_kernel<<<64, 128, 0, stream>>>(z0, fc1w, fc1b, fc2w, fc2b, fc3w, fc3b,
                                       (float*)d_out);
}

// Round 8
// 1024.260 us; speedup vs baseline: 1.6674x; 1.6674x over previous
//
#include <hip/hip_runtime.h>
#include <cfloat>

// N=50000, C=128, H=4, HC=512, E=600000, T=3, Et=200000
// GAT(2x3) -> biLSTM JK -> pool -> MLP. GEMMs in bf16 MFMA (fp32 accum).
// R8: LSTM via per-step lstm_step kernel on the proven 2-blocks/CU GEMM
// skeleton (R2 gemm_lstm): dual GEMM (ih + hh) with sequential 64KB-LDS
// staging, gate-interleaved weights (cell is thread-local in the epilogue),
// gates never hit HBM, h ping-pong bf16 buffers, c f32 (disjoint per block),
// JK score fused. No persistent kernel, no spill (acc[2][4]=32 regs).

typedef __attribute__((ext_vector_type(8))) short short8;
typedef __attribute__((ext_vector_type(4))) float f32x4;

#define DEG_CAP 32   // P(Poisson(4) >= 32) ~ 1e-18

__device__ __forceinline__ float lrelu(float x, float s) { return x > 0.f ? x : s * x; }

__device__ __forceinline__ float sigmf(float x) {
    return __builtin_amdgcn_rcpf(1.f + __expf(-x));
}
__device__ __forceinline__ float tanhf_fast(float x) {
    x = fminf(fmaxf(x, -15.f), 15.f);
    float e = __expf(2.f * x);
    return (e - 1.f) * __builtin_amdgcn_rcpf(e + 1.f);
}

__device__ __forceinline__ unsigned f2bf(float f) {   // RNE f32->bf16 (bits)
    unsigned u = __float_as_uint(f);
    return (u + 0x7FFFu + ((u >> 16) & 1u)) >> 16;
}

// bijective XCD-chunked swizzle (m204): consecutive tiles land on one XCD
__device__ __forceinline__ int xcd_tile(int bid, int nwg) {
    int q = nwg >> 3, r = nwg & 7;
    int xcd = bid & 7, idx = bid >> 3;
    return (xcd < r ? xcd * (q + 1) : r * (q + 1) + (xcd - r) * q) + idx;
}

// stage 128x128 A (f32->bf16, XOR-swizzled) + 128x128 B (bf16) into LDS. 512 thr.
__device__ __forceinline__ void stage_tiles(
    char* ldsA, char* ldsB, const float* __restrict__ A,
    const ushort* __restrict__ Bt, int row0, int col0, int M, int tid)
{
#pragma unroll
    for (int it = 0; it < 4; ++it) {
        int idx = it * 512 + tid;
        int r = idx >> 4, kc = (idx & 15) << 3;
        int row = row0 + r;
        float4 v0 = make_float4(0.f, 0.f, 0.f, 0.f), v1 = v0;
        if (row < M) {
            const float* ap = A + (long)row * 128 + kc;
            v0 = *(const float4*)ap;
            v1 = *(const float4*)(ap + 4);
        }
        uint4 w;
        w.x = f2bf(v0.x) | (f2bf(v0.y) << 16);
        w.y = f2bf(v0.z) | (f2bf(v0.w) << 16);
        w.z = f2bf(v1.x) | (f2bf(v1.y) << 16);
        w.w = f2bf(v1.z) | (f2bf(v1.w) << 16);
        int off = (r * 256 + kc * 2) ^ ((r & 7) << 4);
        *(uint4*)(ldsA + off) = w;
        *(uint4*)(ldsB + off) = *(const uint4*)(Bt + (long)(col0 + r) * 128 + kc);
    }
}

// stage 128x128 bf16 A tile (row-guarded) into XOR-swizzled LDS. 512 thr.
__device__ __forceinline__ void stage_a16(
    char* ldsA, const ushort* __restrict__ A, int row0, int M, int tid)
{
#pragma unroll
    for (int it = 0; it < 4; ++it) {
        int idx = it * 512 + tid;
        int r = idx >> 4, kc = (idx & 15) << 3;
        int row = row0 + r;
        uint4 v = make_uint4(0, 0, 0, 0);
        if (row < M) v = *(const uint4*)(A + (long)row * 128 + kc);
        *(uint4*)(ldsA + ((r * 256 + kc * 2) ^ ((r & 7) << 4))) = v;
    }
}
// stage 128x128 bf16 B tile (unguarded) into XOR-swizzled LDS. 512 thr.
__device__ __forceinline__ void stage_b16(
    char* ldsB, const ushort* __restrict__ B, int tid)
{
#pragma unroll
    for (int it = 0; it < 4; ++it) {
        int idx = it * 512 + tid;
        int r = idx >> 4, kc = (idx & 15) << 3;
        *(uint4*)(ldsB + ((r * 256 + kc * 2) ^ ((r & 7) << 4))) =
            *(const uint4*)(B + (long)r * 128 + kc);
    }
}

// per-wave 32x64 MFMA tile compute (8 waves cover 128x128)
__device__ __forceinline__ void compute_tile(
    const char* ldsA, const char* ldsB, f32x4 acc[2][4],
    int wr, int wc, int lr, int lk)
{
#pragma unroll
    for (int ks = 0; ks < 4; ++ks) {
        int kb = ks * 64 + lk;
        short8 af[2], bfr[4];
#pragma unroll
        for (int i = 0; i < 2; ++i) {
            int r = wr + i * 16 + lr;
            af[i] = *(const short8*)(ldsA + ((r * 256 + kb) ^ ((r & 7) << 4)));
        }
#pragma unroll
        for (int j = 0; j < 4; ++j) {
            int c = wc + j * 16 + lr;
            bfr[j] = *(const short8*)(ldsB + ((c * 256 + kb) ^ ((c & 7) << 4)));
        }
#pragma unroll
        for (int i = 0; i < 2; ++i)
#pragma unroll
            for (int j = 0; j < 4; ++j)
                acc[i][j] = __builtin_amdgcn_mfma_f32_16x16x32_bf16(af[i], bfr[j], acc[i][j], 0, 0, 0);
    }
}

// ---------------- GAT GEMM: xp[M,512] = A @ Bt^T ; fused als/ald (att dots)
__global__ __launch_bounds__(512, 4) void gemm_att(
    const float* __restrict__ A, const ushort* __restrict__ Bt,
    float* __restrict__ C, const float* __restrict__ a_s,
    const float* __restrict__ a_d, float* __restrict__ als,
    float* __restrict__ ald, int M, int nwg)
{
    __shared__ char lds[65536];
    __shared__ float smS[128], smD[128];
    char* ldsA = lds;
    char* ldsB = lds + 32768;
    const int tid = threadIdx.x;
    int tile = xcd_tile(blockIdx.x, nwg);
    int row0 = (tile >> 2) * 128;
    int h = tile & 3;                 // col tile == head
    int col0 = h * 128;
    if (tid < 128) { smS[tid] = 0.f; smD[tid] = 0.f; }
    stage_tiles(ldsA, ldsB, A, Bt, row0, col0, M, tid);
    __syncthreads();

    const int wv = tid >> 6, lane = tid & 63;
    const int wr = (wv & 3) * 32, wc = (wv >> 2) * 64;
    const int lr = lane & 15;
    const int lk = (lane >> 4) << 4;
    f32x4 acc[2][4] = {};
    compute_tile(ldsA, ldsB, acc, wr, wc, lr, lk);

    const float* asl = a_s + h * 128;
    const float* adl = a_d + h * 128;
#pragma unroll
    for (int i = 0; i < 2; ++i) {
#pragma unroll
        for (int q = 0; q < 4; ++q) {
            float ps = 0.f, pd = 0.f;
            int row = row0 + wr + i * 16 + (lane >> 4) * 4 + q;
#pragma unroll
            for (int j = 0; j < 4; ++j) {
                int cc = wc + j * 16 + lr;
                float v = acc[i][j][q];
                ps += v * asl[cc];
                pd += v * adl[cc];
                if (row < M) C[(long)row * 512 + col0 + cc] = v;
            }
#pragma unroll
            for (int off = 8; off; off >>= 1) {
                ps += __shfl_xor(ps, off);
                pd += __shfl_xor(pd, off);
            }
            if (lr == 0) {
                int rl = wr + i * 16 + (lane >> 4) * 4 + q;
                atomicAdd(&smS[rl], ps);
                atomicAdd(&smD[rl], pd);
            }
        }
    }
    __syncthreads();
    if (tid < 128) {
        int row = row0 + tid;
        if (row < M) {
            als[(long)row * 4 + h] = smS[tid];
            ald[(long)row * 4 + h] = smD[tid];
        }
    }
}

// ---------------- fused LSTM step: dual GEMM (ih+hh, permuted B) + cell + JK.
// Grid (RB*4): tile>>2 = row panel, tile&3 = cc (permuted 128-col chunk =
// all 4 gates of channels cc*32..cc*32+31). hprev/hcur: bf16 [N][128]
// ping-pong. cbuf: f32 [N][128], per-block-disjoint channel chunk.
__global__ __launch_bounds__(512, 4) void lstm_step(
    const ushort* __restrict__ Ab, const ushort* __restrict__ Bih,
    const ushort* __restrict__ Bhh, const ushort* __restrict__ hprev,
    ushort* __restrict__ hcur, float* __restrict__ cbuf,
    const float* __restrict__ bi, const float* __restrict__ bh,
    const float* __restrict__ jw, float* __restrict__ score,
    int N, int nwg, int first)
{
    __shared__ char lds[65536];
    __shared__ float ssc[128];
    char* ldsA = lds;
    char* ldsB = lds + 32768;
    const int tid = threadIdx.x;
    int tile = xcd_tile(blockIdx.x, nwg);
    int row0 = (tile >> 2) * 128;
    int cc = tile & 3;
    if (tid < 128) ssc[tid] = 0.f;

    const int wv = tid >> 6, lane = tid & 63;
    const int wr = (wv & 3) * 32, wc = (wv >> 2) * 64;
    const int lr = lane & 15, lg = lane >> 4;
    const int lk = lg << 4;
    f32x4 acc[2][4] = {};

    // pass 1: x @ Wih[cc]
    stage_a16(ldsA, Ab, row0, N, tid);
    stage_b16(ldsB, Bih + (long)cc * 128 * 128, tid);
    __syncthreads();
    compute_tile(ldsA, ldsB, acc, wr, wc, lr, lk);
    // pass 2: hprev @ Whh[cc]
    if (!first) {
        __syncthreads();
        stage_a16(ldsA, hprev, row0, N, tid);
        stage_b16(ldsB, Bhh + (long)cc * 128 * 128, tid);
        __syncthreads();
        compute_tile(ldsA, ldsB, acc, wr, wc, lr, lk);
    }

    // epilogue: j == gate (i,f,g,o); channel = cc*32 + (wc/64)*16 + lr
    const int ch = cc * 32 + (wc >> 6) * 16 + lr;
    const float bI = bi[ch] + bh[ch];
    const float bF = bi[128 + ch] + bh[128 + ch];
    const float bG = bi[256 + ch] + bh[256 + ch];
    const float bO = bi[384 + ch] + bh[384 + ch];
    const float jv = jw[ch];
    float psum[8];
#pragma unroll
    for (int i = 0; i < 2; ++i) {
#pragma unroll
        for (int q = 0; q < 4; ++q) {
            int u = i * 4 + q;
            int row = row0 + wr + i * 16 + lg * 4 + q;
            float p = 0.f;
            if (row < N) {
                long off = (long)row * 128 + ch;
                float cprev = first ? 0.f : cbuf[off];
                float cv = sigmf(acc[i][1][q] + bF) * cprev
                         + sigmf(acc[i][0][q] + bI) * tanhf_fast(acc[i][2][q] + bG);
                float hv = sigmf(acc[i][3][q] + bO) * tanhf_fast(cv);
                cbuf[off] = cv;
                hcur[off] = (ushort)f2bf(hv);
                p = hv * jv;
            }
            psum[u] = p;
        }
    }
    // JK partial: reduce over the 16 lr lanes; ssc indexed by block-local row
#pragma unroll
    for (int u = 0; u < 8; ++u) {
        float p = psum[u];
#pragma unroll
        for (int off = 8; off; off >>= 1) p += __shfl_xor(p, off);
        if (lr == 0)
            atomicAdd(&ssc[wr + (u >> 2) * 16 + lg * 4 + (u & 3)], p);
    }
    __syncthreads();
    if (tid < 128) {
        int row = row0 + tid;
        if (row < N) unsafeAtomicAdd(&score[row], ssc[tid]);
    }
}

// ---------------- weight prepack
__global__ void pack_gatw(const float* __restrict__ gw, ushort* __restrict__ out) {
    int i = blockIdx.x * 256 + threadIdx.x;
    if (i >= 6 * 65536) return;
    int pt = i >> 16, rem = i & 65535, n = rem >> 7, k = rem & 127;
    out[i] = (ushort)f2bf(gw[pt * 65536 + k * 512 + n]);
}
// LSTM weights, gate-interleaved permutation: col' -> orig row g*128+ch
__global__ void pack_lstm(const float* __restrict__ a, const float* __restrict__ b,
                          const float* __restrict__ c, const float* __restrict__ d,
                          ushort* __restrict__ out) {
    int i = blockIdx.x * 256 + threadIdx.x;
    if (i >= 4 * 65536) return;
    const float* p = (i < 65536) ? a : (i < 131072) ? b : (i < 196608) ? c : d;
    int rem = i & 65535;
    int cp = rem >> 7, k = rem & 127;
    int g = (cp >> 4) & 3;
    int ch = ((cp >> 6) << 4) | (cp & 15);
    out[i] = (ushort)f2bf(p[(g * 128 + ch) * 128 + k]);
}
// x f32 -> bf16
__global__ void pack_x(const float* __restrict__ x, ushort* __restrict__ o, long n) {
    long i = ((long)blockIdx.x * 256 + threadIdx.x) * 4;
    if (i >= n) return;
    float4 v = *(const float4*)(x + i);
    ushort4 u;
    u.x = (ushort)f2bf(v.x); u.y = (ushort)f2bf(v.y);
    u.z = (ushort)f2bf(v.z); u.w = (ushort)f2bf(v.w);
    *(ushort4*)(o + i) = u;
}

// ---------------- CSR build: bucket incoming edges by dst (per edge type)
__global__ __launch_bounds__(256) void build_csr(
    const int* __restrict__ srcs, const int* __restrict__ dsts,
    int E, int Et, int N, int* __restrict__ cnt, int* __restrict__ bucket)
{
    int i = blockIdx.x * 256 + threadIdx.x;
    if (i >= E) return;
    int t = i / Et;
    int s = srcs[i];
    int d = dsts[i];
    int slot = atomicAdd(&cnt[t * N + d], 1);
    if (slot < DEG_CAP) bucket[((long)(t * N + d)) * DEG_CAP + slot] = s;
}

// ---------------- fused GAT aggregation: one wave per dst node, depth-2 SW pipe
// dst += (or =) lrelu(msg+bias)/3; on final t also writes bf16 copy for LSTM.
__global__ __launch_bounds__(256) void gat_gather(
    const int* __restrict__ cnt, const int* __restrict__ bucket,
    const float* __restrict__ als, const float* __restrict__ ald,
    const float* __restrict__ xp, const float* __restrict__ bias,
    float* __restrict__ dstb, ushort* __restrict__ out16, int N, int t, int first)
{
    int d = blockIdx.x * 4 + (threadIdx.x >> 6);
    int lane = threadIdx.x & 63;
    if (d >= N) return;
    int deg = min(cnt[t * N + d], DEG_CAP);
    int s = d;
    if (lane < deg) s = bucket[((long)(t * N + d)) * DEG_CAP + lane];
    bool act = (lane <= deg);
    float4 ad = *(const float4*)(ald + (long)d * 4);
    float l0 = -FLT_MAX, l1 = -FLT_MAX, l2 = -FLT_MAX, l3 = -FLT_MAX;
    if (act) {
        float4 as = *(const float4*)(als + (long)s * 4);
        l0 = lrelu(as.x + ad.x, 0.2f);
        l1 = lrelu(as.y + ad.y, 0.2f);
        l2 = lrelu(as.z + ad.z, 0.2f);
        l3 = lrelu(as.w + ad.w, 0.2f);
    }
    float m0 = l0, m1 = l1, m2 = l2, m3 = l3;
#pragma unroll
    for (int off = 32; off; off >>= 1) {
        m0 = fmaxf(m0, __shfl_xor(m0, off));
        m1 = fmaxf(m1, __shfl_xor(m1, off));
        m2 = fmaxf(m2, __shfl_xor(m2, off));
        m3 = fmaxf(m3, __shfl_xor(m3, off));
    }
    float e0 = 0.f, e1 = 0.f, e2 = 0.f, e3 = 0.f;
    if (act) {
        e0 = __expf(l0 - m0); e1 = __expf(l1 - m1);
        e2 = __expf(l2 - m2); e3 = __expf(l3 - m3);
    }
    float s0 = e0, s1 = e1, s2 = e2, s3 = e3;
#pragma unroll
    for (int off = 32; off; off >>= 1) {
        s0 += __shfl_xor(s0, off);
        s1 += __shfl_xor(s1, off);
        s2 += __shfl_xor(s2, off);
        s3 += __shfl_xor(s3, off);
    }
    float a0 = 0.25f * e0 / s0, a1 = 0.25f * e1 / s1;
    float a2 = 0.25f * e2 / s2, a3 = 0.25f * e3 / s3;

    // depth-2 software pipeline over incoming edges (+self)
    float acc0 = 0.f, acc1 = 0.f;
    int sj = __shfl(s, 0);
    const float* xs = xp + (long)sj * 512;
    float c0 = xs[lane],       c1 = xs[64 + lane];
    float c2 = xs[128 + lane], c3 = xs[192 + lane];
    float c4 = xs[256 + lane], c5 = xs[320 + lane];
    float c6 = xs[384 + lane], c7 = xs[448 + lane];
    for (int j = 0; j < deg; ++j) {
        int sn = __shfl(s, j + 1);
        const float* xn = xp + (long)sn * 512;
        float n0 = xn[lane],       n1 = xn[64 + lane];
        float n2 = xn[128 + lane], n3 = xn[192 + lane];
        float n4 = xn[256 + lane], n5 = xn[320 + lane];
        float n6 = xn[384 + lane], n7 = xn[448 + lane];
        float w0 = __shfl(a0, j), w1 = __shfl(a1, j);
        float w2 = __shfl(a2, j), w3 = __shfl(a3, j);
        acc0 += w0 * c0 + w1 * c2 + w2 * c4 + w3 * c6;
        acc1 += w0 * c1 + w1 * c3 + w2 * c5 + w3 * c7;
        c0 = n0; c1 = n1; c2 = n2; c3 = n3;
        c4 = n4; c5 = n5; c6 = n6; c7 = n7;
    }
    float w0 = __shfl(a0, deg), w1 = __shfl(a1, deg);
    float w2 = __shfl(a2, deg), w3 = __shfl(a3, deg);
    acc0 += w0 * c0 + w1 * c2 + w2 * c4 + w3 * c6;
    acc1 += w0 * c1 + w1 * c3 + w2 * c5 + w3 * c7;

    float r0 = lrelu(acc0 + bias[lane], 0.01f) * (1.f / 3.f);
    float r1 = lrelu(acc1 + bias[lane + 64], 0.01f) * (1.f / 3.f);
    float* ap = dstb + (long)d * 128;
    float f0, f1;
    if (first) { f0 = r0; f1 = r1; }
    else       { f0 = ap[lane] + r0; f1 = ap[lane + 64] + r1; }
    ap[lane] = f0; ap[lane + 64] = f1;
    if (out16) {
        out16[(long)d * 128 + lane]      = (ushort)f2bf(f0);
        out16[(long)d * 128 + 64 + lane] = (ushort)f2bf(f1);
    }
}

__global__ void jk_kernel(const float* __restrict__ score, const float* __restrict__ x0,
                          const float* __restrict__ x1, const float* __restrict__ x2,
                          float* __restrict__ xjk, int N)
{
    long i = (long)blockIdx.x * 256 + threadIdx.x;
    long n = i >> 7;
    if (n >= N) return;
    float s0 = score[n], s1 = score[N + n], s2 = score[2L * N + n];
    float m = fmaxf(s0, fmaxf(s1, s2));
    float e0 = expf(s0 - m), e1 = expf(s1 - m), e2 = expf(s2 - m);
    float inv = 1.f / (e0 + e1 + e2);
    xjk[i] = (e0 * x0[i] + e1 * x1[i] + e2 * x2[i]) * inv;
}

// z0 init: zeros + ptype in col 128
__global__ void init_z0(const float* __restrict__ ptype, float* __restrict__ z0) {
    int i = blockIdx.x * 128 + threadIdx.x;
    if (i < 64 * 129) z0[i] = ((i % 129) == 128) ? ptype[i / 129] : 0.f;
}

// parallel pool: 64-node chunks, flush on graph boundary
__global__ __launch_bounds__(128) void pool2(
    const float* __restrict__ xjk, const int* __restrict__ batch,
    float* __restrict__ z0, int N)
{
    int c = threadIdx.x;
    int n0 = blockIdx.x * 64;
    if (n0 >= N) return;
    int n1 = min(n0 + 64, N);
    float s = 0.f;
    int g = batch[n0];
    for (int n = n0; n < n1; ++n) {
        int b = batch[n];
        if (b != g) { unsafeAtomicAdd(&z0[g * 129 + c], s); s = 0.f; g = b; }
        s += xjk[(long)n * 128 + c];
    }
    unsafeAtomicAdd(&z0[g * 129 + c], s);
}

__global__ __launch_bounds__(128) void mlp_kernel(
    const float* __restrict__ z0, const float* __restrict__ w1, const float* __restrict__ b1,
    const float* __restrict__ w2, const float* __restrict__ b2,
    const float* __restrict__ w3, const float* __restrict__ b3,
    float* __restrict__ out)
{
    int gidx = blockIdx.x, tid = threadIdx.x;
    __shared__ float zin[129], z1[80], z2[80];
    zin[tid] = z0[gidx * 129 + tid];
    if (tid == 0) zin[128] = z0[gidx * 129 + 128];
    __syncthreads();
    if (tid < 80) {
        float s = b1[tid];
        for (int k = 0; k < 129; ++k) s += zin[k] * w1[k * 80 + tid];
        z1[tid] = lrelu(s, 0.01f);
    }
    __syncthreads();
    if (tid < 80) {
        float s = b2[tid];
        for (int k = 0; k < 80; ++k) s += z1[k] * w2[k * 80 + tid];
        z2[tid] = lrelu(s, 0.01f);
    }
    __syncthreads();
    if (tid < 10) {
        float s = b3[tid];
        for (int k = 0; k < 80; ++k) s += z2[k] * w3[k * 10 + tid];
        out[gidx * 10 + tid] = s;
    }
}

extern "C" void kernel_launch(void* const* d_in, const int* in_sizes, int n_in,
                              void* d_out, int out_size, void* d_ws, size_t ws_size,
                              hipStream_t stream)
{
    (void)n_in; (void)out_size; (void)ws_size;
    const float* x      = (const float*)d_in[0];
    const int*   ei     = (const int*)d_in[1];
    const int*   batch  = (const int*)d_in[2];
    const float* ptype  = (const float*)d_in[3];
    const float* gatW   = (const float*)d_in[4];
    const float* gatAs  = (const float*)d_in[5];
    const float* gatAd  = (const float*)d_in[6];
    const float* gatB   = (const float*)d_in[7];
    const float* w_ih_fw = (const float*)d_in[8];
    const float* w_hh_fw = (const float*)d_in[9];
    const float* b_ih_fw = (const float*)d_in[10];
    const float* b_hh_fw = (const float*)d_in[11];
    const float* w_ih_bw = (const float*)d_in[12];
    const float* w_hh_bw = (const float*)d_in[13];
    const float* b_ih_bw = (const float*)d_in[14];
    const float* b_hh_bw = (const float*)d_in[15];
    const float* jkw    = (const float*)d_in[16];
    const float* fc1w   = (const float*)d_in[18];
    const float* fc1b   = (const float*)d_in[19];
    const float* fc2w   = (const float*)d_in[20];
    const float* fc2b   = (const float*)d_in[21];
    const float* fc3w   = (const float*)d_in[22];
    const float* fc3b   = (const float*)d_in[23];

    const int N = in_sizes[0] / 128;
    const int E = in_sizes[1] / 2;
    const int Et = E / 3;
    const long NC = (long)N * 128;

    float* w = (float*)d_ws;
    float* xp   = w; w += (long)N * 512;    // GAT projections; LSTM: h0/h1 alias
    float* l1   = w; w += NC;
    float* l2   = w; w += NC;
    float* accb = w; w += NC;               // xjk
    float* outm = w; w += NC;               // GAT: CSR cnt+bucket; LSTM: c state
    ushort* xb16 = (ushort*)w; w += 3L * N * 64;   // [3][N][128] bf16 seq
    float* als  = w; w += (long)N * 4;
    float* ald  = w; w += (long)N * 4;
    float* score = w; w += 3L * N;
    ushort* gwt = (ushort*)w; w += 6 * 65536 / 2;   // bf16 GAT weights [6][512][128]
    ushort* lwt = (ushort*)w; w += 4 * 65536 / 2;   // bf16 LSTM weights (permuted)
    float* z0   = w; w += 64 * 129 + 4;

    // CSR aliases the outm region (GAT phase only); LSTM reuses outm as cbuf
    int* cnt    = (int*)outm;
    int* bucket = cnt + 3L * N;
    // h ping-pong buffers alias xp (free after GAT phase)
    ushort* h0 = (ushort*)xp;
    ushort* h1 = h0 + NC;

    pack_gatw<<<(6 * 65536 + 255) / 256, 256, 0, stream>>>(gatW, gwt);
    pack_lstm<<<(4 * 65536 + 255) / 256, 256, 0, stream>>>(w_ih_fw, w_hh_fw, w_ih_bw, w_hh_bw, lwt);
    pack_x<<<(int)((NC / 4 + 255) / 256), 256, 0, stream>>>(x, xb16, NC);
    hipMemsetAsync(score, 0, sizeof(float) * 3 * N, stream);
    hipMemsetAsync(cnt, 0, sizeof(int) * 3 * N, stream);
    build_csr<<<(E + 255) / 256, 256, 0, stream>>>(ei, ei + E, E, Et, N, cnt, bucket);

    const int RB = (N + 127) / 128;
    const int nwg = RB * 4;
    const int ncb = (int)((NC + 255) / 256);

    // ---- GAT layers
    const float* cur = x;
    for (int p = 0; p < 2; ++p) {
        float* dstb = (p == 0) ? l1 : l2;
        ushort* d16 = xb16 + (long)(p + 1) * N * 128;
        for (int t = 0; t < 3; ++t) {
            int pt = p * 3 + t;
            gemm_att<<<nwg, 512, 0, stream>>>(cur, gwt + (long)pt * 65536, xp,
                                              gatAs + pt * 512, gatAd + pt * 512,
                                              als, ald, N, nwg);
            gat_gather<<<(N + 3) / 4, 256, 0, stream>>>(cnt, bucket, als, ald, xp,
                                                        gatB + pt * 128, dstb,
                                                        (t == 2) ? d16 : nullptr,
                                                        N, t, t == 0);
        }
        cur = dstb;
    }

    // ---- fused bi-LSTM via per-step dual-GEMM + cell + JK score
    float* cbuf = outm;                    // CSR dead now
    for (int dir = 0; dir < 2; ++dir) {
        const ushort* Bih = lwt + (long)(dir ? 2 : 0) * 65536;
        const ushort* Bhh = lwt + (long)(dir ? 3 : 1) * 65536;
        const float* bi = dir ? b_ih_bw : b_ih_fw;
        const float* bh = dir ? b_hh_bw : b_hh_fw;
        const float* jw = jkw + (dir ? 128 : 0);
        ushort* hp = h0;
        ushort* hc = h1;
        for (int j = 0; j < 3; ++j) {
            int l = dir ? (2 - j) : j;
            const ushort* Ab = xb16 + (long)l * N * 128;
            lstm_step<<<nwg, 512, 0, stream>>>(Ab, Bih, Bhh, hp, hc, cbuf,
                                               bi, bh, jw, score + (long)l * N,
                                               N, nwg, j == 0);
            ushort* tmp = hp; hp = hc; hc = tmp;
        }
    }

    // ---- JK softmax-weighted sum, pool, MLP
    jk_kernel<<<ncb, 256, 0, stream>>>(score, x, l1, l2, accb, N);
    init_z0<<<65, 128, 0, stream>>>(ptype, z0);
    pool2<<<(N + 63) / 64, 128, 0, stream>>>(accb, batch, z0, N);
    mlp_kernel<<<64, 128, 0, stream>>>(z0, fc1w, fc1b, fc2w, fc2b, fc3w, fc3b,
                                       (float*)d_out);
}

// Round 9
// 793.273 us; speedup vs baseline: 2.1529x; 1.2912x over previous
//
#include <hip/hip_runtime.h>
#include <cfloat>

// N=50000, C=128, H=4, HC=512, E=600000, T=3, Et=200000
// GAT(2x3) -> biLSTM JK -> pool -> MLP. GEMMs in bf16 MFMA (fp32 accum).
// R9: xp stored as bf16 (halves the gather's HBM bytes -- its only consumer),
// gat_gather reads rows as 4 x uint/lane (2 bf16 ch each, full coalescing),
// gemm_att writes bf16 C (halved write traffic). LSTM phase = R8 (verified
// no-spill lstm_step skeleton).

typedef __attribute__((ext_vector_type(8))) short short8;
typedef __attribute__((ext_vector_type(4))) float f32x4;

#define DEG_CAP 32   // P(Poisson(4) >= 32) ~ 1e-18

__device__ __forceinline__ float lrelu(float x, float s) { return x > 0.f ? x : s * x; }

__device__ __forceinline__ float sigmf(float x) {
    return __builtin_amdgcn_rcpf(1.f + __expf(-x));
}
__device__ __forceinline__ float tanhf_fast(float x) {
    x = fminf(fmaxf(x, -15.f), 15.f);
    float e = __expf(2.f * x);
    return (e - 1.f) * __builtin_amdgcn_rcpf(e + 1.f);
}

__device__ __forceinline__ unsigned f2bf(float f) {   // RNE f32->bf16 (bits)
    unsigned u = __float_as_uint(f);
    return (u + 0x7FFFu + ((u >> 16) & 1u)) >> 16;
}
__device__ __forceinline__ float bflo(unsigned u) {   // low bf16 of packed pair
    return __uint_as_float(u << 16);
}
__device__ __forceinline__ float bfhi(unsigned u) {   // high bf16 of packed pair
    return __uint_as_float(u & 0xFFFF0000u);
}

// bijective XCD-chunked swizzle (m204): consecutive tiles land on one XCD
__device__ __forceinline__ int xcd_tile(int bid, int nwg) {
    int q = nwg >> 3, r = nwg & 7;
    int xcd = bid & 7, idx = bid >> 3;
    return (xcd < r ? xcd * (q + 1) : r * (q + 1) + (xcd - r) * q) + idx;
}

// stage 128x128 A (f32->bf16, XOR-swizzled) + 128x128 B (bf16) into LDS. 512 thr.
__device__ __forceinline__ void stage_tiles(
    char* ldsA, char* ldsB, const float* __restrict__ A,
    const ushort* __restrict__ Bt, int row0, int col0, int M, int tid)
{
#pragma unroll
    for (int it = 0; it < 4; ++it) {
        int idx = it * 512 + tid;
        int r = idx >> 4, kc = (idx & 15) << 3;
        int row = row0 + r;
        float4 v0 = make_float4(0.f, 0.f, 0.f, 0.f), v1 = v0;
        if (row < M) {
            const float* ap = A + (long)row * 128 + kc;
            v0 = *(const float4*)ap;
            v1 = *(const float4*)(ap + 4);
        }
        uint4 w;
        w.x = f2bf(v0.x) | (f2bf(v0.y) << 16);
        w.y = f2bf(v0.z) | (f2bf(v0.w) << 16);
        w.z = f2bf(v1.x) | (f2bf(v1.y) << 16);
        w.w = f2bf(v1.z) | (f2bf(v1.w) << 16);
        int off = (r * 256 + kc * 2) ^ ((r & 7) << 4);
        *(uint4*)(ldsA + off) = w;
        *(uint4*)(ldsB + off) = *(const uint4*)(Bt + (long)(col0 + r) * 128 + kc);
    }
}

// stage 128x128 bf16 A tile (row-guarded) into XOR-swizzled LDS. 512 thr.
__device__ __forceinline__ void stage_a16(
    char* ldsA, const ushort* __restrict__ A, int row0, int M, int tid)
{
#pragma unroll
    for (int it = 0; it < 4; ++it) {
        int idx = it * 512 + tid;
        int r = idx >> 4, kc = (idx & 15) << 3;
        int row = row0 + r;
        uint4 v = make_uint4(0, 0, 0, 0);
        if (row < M) v = *(const uint4*)(A + (long)row * 128 + kc);
        *(uint4*)(ldsA + ((r * 256 + kc * 2) ^ ((r & 7) << 4))) = v;
    }
}
// stage 128x128 bf16 B tile (unguarded) into XOR-swizzled LDS. 512 thr.
__device__ __forceinline__ void stage_b16(
    char* ldsB, const ushort* __restrict__ B, int tid)
{
#pragma unroll
    for (int it = 0; it < 4; ++it) {
        int idx = it * 512 + tid;
        int r = idx >> 4, kc = (idx & 15) << 3;
        *(uint4*)(ldsB + ((r * 256 + kc * 2) ^ ((r & 7) << 4))) =
            *(const uint4*)(B + (long)r * 128 + kc);
    }
}

// per-wave 32x64 MFMA tile compute (8 waves cover 128x128)
__device__ __forceinline__ void compute_tile(
    const char* ldsA, const char* ldsB, f32x4 acc[2][4],
    int wr, int wc, int lr, int lk)
{
#pragma unroll
    for (int ks = 0; ks < 4; ++ks) {
        int kb = ks * 64 + lk;
        short8 af[2], bfr[4];
#pragma unroll
        for (int i = 0; i < 2; ++i) {
            int r = wr + i * 16 + lr;
            af[i] = *(const short8*)(ldsA + ((r * 256 + kb) ^ ((r & 7) << 4)));
        }
#pragma unroll
        for (int j = 0; j < 4; ++j) {
            int c = wc + j * 16 + lr;
            bfr[j] = *(const short8*)(ldsB + ((c * 256 + kb) ^ ((c & 7) << 4)));
        }
#pragma unroll
        for (int i = 0; i < 2; ++i)
#pragma unroll
            for (int j = 0; j < 4; ++j)
                acc[i][j] = __builtin_amdgcn_mfma_f32_16x16x32_bf16(af[i], bfr[j], acc[i][j], 0, 0, 0);
    }
}

// ---------------- GAT GEMM: xp16[M,512](bf16) = A @ Bt^T ; fused als/ald
__global__ __launch_bounds__(512, 4) void gemm_att(
    const float* __restrict__ A, const ushort* __restrict__ Bt,
    ushort* __restrict__ C16, const float* __restrict__ a_s,
    const float* __restrict__ a_d, float* __restrict__ als,
    float* __restrict__ ald, int M, int nwg)
{
    __shared__ char lds[65536];
    __shared__ float smS[128], smD[128];
    char* ldsA = lds;
    char* ldsB = lds + 32768;
    const int tid = threadIdx.x;
    int tile = xcd_tile(blockIdx.x, nwg);
    int row0 = (tile >> 2) * 128;
    int h = tile & 3;                 // col tile == head
    int col0 = h * 128;
    if (tid < 128) { smS[tid] = 0.f; smD[tid] = 0.f; }
    stage_tiles(ldsA, ldsB, A, Bt, row0, col0, M, tid);
    __syncthreads();

    const int wv = tid >> 6, lane = tid & 63;
    const int wr = (wv & 3) * 32, wc = (wv >> 2) * 64;
    const int lr = lane & 15;
    const int lk = (lane >> 4) << 4;
    f32x4 acc[2][4] = {};
    compute_tile(ldsA, ldsB, acc, wr, wc, lr, lk);

    const float* asl = a_s + h * 128;
    const float* adl = a_d + h * 128;
#pragma unroll
    for (int i = 0; i < 2; ++i) {
#pragma unroll
        for (int q = 0; q < 4; ++q) {
            float ps = 0.f, pd = 0.f;
            int row = row0 + wr + i * 16 + (lane >> 4) * 4 + q;
#pragma unroll
            for (int j = 0; j < 4; ++j) {
                int cc = wc + j * 16 + lr;
                float v = acc[i][j][q];
                ps += v * asl[cc];
                pd += v * adl[cc];
                if (row < M) C16[(long)row * 512 + col0 + cc] = (ushort)f2bf(v);
            }
#pragma unroll
            for (int off = 8; off; off >>= 1) {
                ps += __shfl_xor(ps, off);
                pd += __shfl_xor(pd, off);
            }
            if (lr == 0) {
                int rl = wr + i * 16 + (lane >> 4) * 4 + q;
                atomicAdd(&smS[rl], ps);
                atomicAdd(&smD[rl], pd);
            }
        }
    }
    __syncthreads();
    if (tid < 128) {
        int row = row0 + tid;
        if (row < M) {
            als[(long)row * 4 + h] = smS[tid];
            ald[(long)row * 4 + h] = smD[tid];
        }
    }
}

// ---------------- fused LSTM step: dual GEMM (ih+hh, permuted B) + cell + JK.
__global__ __launch_bounds__(512, 4) void lstm_step(
    const ushort* __restrict__ Ab, const ushort* __restrict__ Bih,
    const ushort* __restrict__ Bhh, const ushort* __restrict__ hprev,
    ushort* __restrict__ hcur, float* __restrict__ cbuf,
    const float* __restrict__ bi, const float* __restrict__ bh,
    const float* __restrict__ jw, float* __restrict__ score,
    int N, int nwg, int first)
{
    __shared__ char lds[65536];
    __shared__ float ssc[128];
    char* ldsA = lds;
    char* ldsB = lds + 32768;
    const int tid = threadIdx.x;
    int tile = xcd_tile(blockIdx.x, nwg);
    int row0 = (tile >> 2) * 128;
    int cc = tile & 3;
    if (tid < 128) ssc[tid] = 0.f;

    const int wv = tid >> 6, lane = tid & 63;
    const int wr = (wv & 3) * 32, wc = (wv >> 2) * 64;
    const int lr = lane & 15, lg = lane >> 4;
    const int lk = lg << 4;
    f32x4 acc[2][4] = {};

    // pass 1: x @ Wih[cc]
    stage_a16(ldsA, Ab, row0, N, tid);
    stage_b16(ldsB, Bih + (long)cc * 128 * 128, tid);
    __syncthreads();
    compute_tile(ldsA, ldsB, acc, wr, wc, lr, lk);
    // pass 2: hprev @ Whh[cc]
    if (!first) {
        __syncthreads();
        stage_a16(ldsA, hprev, row0, N, tid);
        stage_b16(ldsB, Bhh + (long)cc * 128 * 128, tid);
        __syncthreads();
        compute_tile(ldsA, ldsB, acc, wr, wc, lr, lk);
    }

    // epilogue: j == gate (i,f,g,o); channel = cc*32 + (wc/64)*16 + lr
    const int ch = cc * 32 + (wc >> 6) * 16 + lr;
    const float bI = bi[ch] + bh[ch];
    const float bF = bi[128 + ch] + bh[128 + ch];
    const float bG = bi[256 + ch] + bh[256 + ch];
    const float bO = bi[384 + ch] + bh[384 + ch];
    const float jv = jw[ch];
    float psum[8];
#pragma unroll
    for (int i = 0; i < 2; ++i) {
#pragma unroll
        for (int q = 0; q < 4; ++q) {
            int u = i * 4 + q;
            int row = row0 + wr + i * 16 + lg * 4 + q;
            float p = 0.f;
            if (row < N) {
                long off = (long)row * 128 + ch;
                float cprev = first ? 0.f : cbuf[off];
                float cv = sigmf(acc[i][1][q] + bF) * cprev
                         + sigmf(acc[i][0][q] + bI) * tanhf_fast(acc[i][2][q] + bG);
                float hv = sigmf(acc[i][3][q] + bO) * tanhf_fast(cv);
                cbuf[off] = cv;
                hcur[off] = (ushort)f2bf(hv);
                p = hv * jv;
            }
            psum[u] = p;
        }
    }
#pragma unroll
    for (int u = 0; u < 8; ++u) {
        float p = psum[u];
#pragma unroll
        for (int off = 8; off; off >>= 1) p += __shfl_xor(p, off);
        if (lr == 0)
            atomicAdd(&ssc[wr + (u >> 2) * 16 + lg * 4 + (u & 3)], p);
    }
    __syncthreads();
    if (tid < 128) {
        int row = row0 + tid;
        if (row < N) unsafeAtomicAdd(&score[row], ssc[tid]);
    }
}

// ---------------- weight prepack
__global__ void pack_gatw(const float* __restrict__ gw, ushort* __restrict__ out) {
    int i = blockIdx.x * 256 + threadIdx.x;
    if (i >= 6 * 65536) return;
    int pt = i >> 16, rem = i & 65535, n = rem >> 7, k = rem & 127;
    out[i] = (ushort)f2bf(gw[pt * 65536 + k * 512 + n]);
}
// LSTM weights, gate-interleaved permutation: col' -> orig row g*128+ch
__global__ void pack_lstm(const float* __restrict__ a, const float* __restrict__ b,
                          const float* __restrict__ c, const float* __restrict__ d,
                          ushort* __restrict__ out) {
    int i = blockIdx.x * 256 + threadIdx.x;
    if (i >= 4 * 65536) return;
    const float* p = (i < 65536) ? a : (i < 131072) ? b : (i < 196608) ? c : d;
    int rem = i & 65535;
    int cp = rem >> 7, k = rem & 127;
    int g = (cp >> 4) & 3;
    int ch = ((cp >> 6) << 4) | (cp & 15);
    out[i] = (ushort)f2bf(p[(g * 128 + ch) * 128 + k]);
}
// x f32 -> bf16
__global__ void pack_x(const float* __restrict__ x, ushort* __restrict__ o, long n) {
    long i = ((long)blockIdx.x * 256 + threadIdx.x) * 4;
    if (i >= n) return;
    float4 v = *(const float4*)(x + i);
    ushort4 u;
    u.x = (ushort)f2bf(v.x); u.y = (ushort)f2bf(v.y);
    u.z = (ushort)f2bf(v.z); u.w = (ushort)f2bf(v.w);
    *(ushort4*)(o + i) = u;
}

// ---------------- CSR build: bucket incoming edges by dst (per edge type)
__global__ __launch_bounds__(256) void build_csr(
    const int* __restrict__ srcs, const int* __restrict__ dsts,
    int E, int Et, int N, int* __restrict__ cnt, int* __restrict__ bucket)
{
    int i = blockIdx.x * 256 + threadIdx.x;
    if (i >= E) return;
    int t = i / Et;
    int s = srcs[i];
    int d = dsts[i];
    int slot = atomicAdd(&cnt[t * N + d], 1);
    if (slot < DEG_CAP) bucket[((long)(t * N + d)) * DEG_CAP + slot] = s;
}

// ---------------- fused GAT aggregation: one wave per dst node, depth-2 SW pipe
// xp16 rows read as 4 x uint/lane (2 bf16 ch each). Lane owns output channels
// 2*lane and 2*lane+1. dst += (or =) lrelu(msg+bias)/3; final t writes bf16.
__global__ __launch_bounds__(256) void gat_gather(
    const int* __restrict__ cnt, const int* __restrict__ bucket,
    const float* __restrict__ als, const float* __restrict__ ald,
    const ushort* __restrict__ xp16, const float* __restrict__ bias,
    float* __restrict__ dstb, ushort* __restrict__ out16, int N, int t, int first)
{
    int d = blockIdx.x * 4 + (threadIdx.x >> 6);
    int lane = threadIdx.x & 63;
    if (d >= N) return;
    int deg = min(cnt[t * N + d], DEG_CAP);
    int s = d;
    if (lane < deg) s = bucket[((long)(t * N + d)) * DEG_CAP + lane];
    bool act = (lane <= deg);
    float4 ad = *(const float4*)(ald + (long)d * 4);
    float l0 = -FLT_MAX, l1 = -FLT_MAX, l2 = -FLT_MAX, l3 = -FLT_MAX;
    if (act) {
        float4 as = *(const float4*)(als + (long)s * 4);
        l0 = lrelu(as.x + ad.x, 0.2f);
        l1 = lrelu(as.y + ad.y, 0.2f);
        l2 = lrelu(as.z + ad.z, 0.2f);
        l3 = lrelu(as.w + ad.w, 0.2f);
    }
    float m0 = l0, m1 = l1, m2 = l2, m3 = l3;
#pragma unroll
    for (int off = 32; off; off >>= 1) {
        m0 = fmaxf(m0, __shfl_xor(m0, off));
        m1 = fmaxf(m1, __shfl_xor(m1, off));
        m2 = fmaxf(m2, __shfl_xor(m2, off));
        m3 = fmaxf(m3, __shfl_xor(m3, off));
    }
    float e0 = 0.f, e1 = 0.f, e2 = 0.f, e3 = 0.f;
    if (act) {
        e0 = __expf(l0 - m0); e1 = __expf(l1 - m1);
        e2 = __expf(l2 - m2); e3 = __expf(l3 - m3);
    }
    float s0 = e0, s1 = e1, s2 = e2, s3 = e3;
#pragma unroll
    for (int off = 32; off; off >>= 1) {
        s0 += __shfl_xor(s0, off);
        s1 += __shfl_xor(s1, off);
        s2 += __shfl_xor(s2, off);
        s3 += __shfl_xor(s3, off);
    }
    float a0 = 0.25f * e0 / s0, a1 = 0.25f * e1 / s1;
    float a2 = 0.25f * e2 / s2, a3 = 0.25f * e3 / s3;

    // depth-2 software pipeline; row = 256 uints, head h at uints h*64..h*64+63
    float accL = 0.f, accH = 0.f;
    int sj = __shfl(s, 0);
    const uint* xs = (const uint*)(xp16 + (long)sj * 512);
    uint c0 = xs[lane], c1 = xs[64 + lane], c2 = xs[128 + lane], c3 = xs[192 + lane];
    for (int j = 0; j < deg; ++j) {
        int sn = __shfl(s, j + 1);
        const uint* xn = (const uint*)(xp16 + (long)sn * 512);
        uint n0 = xn[lane], n1 = xn[64 + lane], n2 = xn[128 + lane], n3 = xn[192 + lane];
        float w0 = __shfl(a0, j), w1 = __shfl(a1, j);
        float w2 = __shfl(a2, j), w3 = __shfl(a3, j);
        accL += w0 * bflo(c0) + w1 * bflo(c1) + w2 * bflo(c2) + w3 * bflo(c3);
        accH += w0 * bfhi(c0) + w1 * bfhi(c1) + w2 * bfhi(c2) + w3 * bfhi(c3);
        c0 = n0; c1 = n1; c2 = n2; c3 = n3;
    }
    float w0 = __shfl(a0, deg), w1 = __shfl(a1, deg);
    float w2 = __shfl(a2, deg), w3 = __shfl(a3, deg);
    accL += w0 * bflo(c0) + w1 * bflo(c1) + w2 * bflo(c2) + w3 * bflo(c3);
    accH += w0 * bfhi(c0) + w1 * bfhi(c1) + w2 * bfhi(c2) + w3 * bfhi(c3);

    int chL = 2 * lane;
    float r0 = lrelu(accL + bias[chL], 0.01f) * (1.f / 3.f);
    float r1 = lrelu(accH + bias[chL + 1], 0.01f) * (1.f / 3.f);
    float2* ap = (float2*)(dstb + (long)d * 128) + lane;
    float2 f;
    if (first) { f.x = r0; f.y = r1; }
    else       { float2 prev = *ap; f.x = prev.x + r0; f.y = prev.y + r1; }
    *ap = f;
    if (out16) {
        ushort2 u2;
        u2.x = (ushort)f2bf(f.x);
        u2.y = (ushort)f2bf(f.y);
        *((ushort2*)(out16 + (long)d * 128) + lane) = u2;
    }
}

__global__ void jk_kernel(const float* __restrict__ score, const float* __restrict__ x0,
                          const float* __restrict__ x1, const float* __restrict__ x2,
                          float* __restrict__ xjk, int N)
{
    long i = (long)blockIdx.x * 256 + threadIdx.x;
    long n = i >> 7;
    if (n >= N) return;
    float s0 = score[n], s1 = score[N + n], s2 = score[2L * N + n];
    float m = fmaxf(s0, fmaxf(s1, s2));
    float e0 = expf(s0 - m), e1 = expf(s1 - m), e2 = expf(s2 - m);
    float inv = 1.f / (e0 + e1 + e2);
    xjk[i] = (e0 * x0[i] + e1 * x1[i] + e2 * x2[i]) * inv;
}

// z0 init: zeros + ptype in col 128
__global__ void init_z0(const float* __restrict__ ptype, float* __restrict__ z0) {
    int i = blockIdx.x * 128 + threadIdx.x;
    if (i < 64 * 129) z0[i] = ((i % 129) == 128) ? ptype[i / 129] : 0.f;
}

// parallel pool: 64-node chunks, flush on graph boundary
__global__ __launch_bounds__(128) void pool2(
    const float* __restrict__ xjk, const int* __restrict__ batch,
    float* __restrict__ z0, int N)
{
    int c = threadIdx.x;
    int n0 = blockIdx.x * 64;
    if (n0 >= N) return;
    int n1 = min(n0 + 64, N);
    float s = 0.f;
    int g = batch[n0];
    for (int n = n0; n < n1; ++n) {
        int b = batch[n];
        if (b != g) { unsafeAtomicAdd(&z0[g * 129 + c], s); s = 0.f; g = b; }
        s += xjk[(long)n * 128 + c];
    }
    unsafeAtomicAdd(&z0[g * 129 + c], s);
}

__global__ __launch_bounds__(128) void mlp_kernel(
    const float* __restrict__ z0, const float* __restrict__ w1, const float* __restrict__ b1,
    const float* __restrict__ w2, const float* __restrict__ b2,
    const float* __restrict__ w3, const float* __restrict__ b3,
    float* __restrict__ out)
{
    int gidx = blockIdx.x, tid = threadIdx.x;
    __shared__ float zin[129], z1[80], z2[80];
    zin[tid] = z0[gidx * 129 + tid];
    if (tid == 0) zin[128] = z0[gidx * 129 + 128];
    __syncthreads();
    if (tid < 80) {
        float s = b1[tid];
        for (int k = 0; k < 129; ++k) s += zin[k] * w1[k * 80 + tid];
        z1[tid] = lrelu(s, 0.01f);
    }
    __syncthreads();
    if (tid < 80) {
        float s = b2[tid];
        for (int k = 0; k < 80; ++k) s += z1[k] * w2[k * 80 + tid];
        z2[tid] = lrelu(s, 0.01f);
    }
    __syncthreads();
    if (tid < 10) {
        float s = b3[tid];
        for (int k = 0; k < 80; ++k) s += z2[k] * w3[k * 10 + tid];
        out[gidx * 10 + tid] = s;
    }
}

extern "C" void kernel_launch(void* const* d_in, const int* in_sizes, int n_in,
                              void* d_out, int out_size, void* d_ws, size_t ws_size,
                              hipStream_t stream)
{
    (void)n_in; (void)out_size; (void)ws_size;
    const float* x      = (const float*)d_in[0];
    const int*   ei     = (const int*)d_in[1];
    const int*   batch  = (const int*)d_in[2];
    const float* ptype  = (const float*)d_in[3];
    const float* gatW   = (const float*)d_in[4];
    const float* gatAs  = (const float*)d_in[5];
    const float* gatAd  = (const float*)d_in[6];
    const float* gatB   = (const float*)d_in[7];
    const float* w_ih_fw = (const float*)d_in[8];
    const float* w_hh_fw = (const float*)d_in[9];
    const float* b_ih_fw = (const float*)d_in[10];
    const float* b_hh_fw = (const float*)d_in[11];
    const float* w_ih_bw = (const float*)d_in[12];
    const float* w_hh_bw = (const float*)d_in[13];
    const float* b_ih_bw = (const float*)d_in[14];
    const float* b_hh_bw = (const float*)d_in[15];
    const float* jkw    = (const float*)d_in[16];
    const float* fc1w   = (const float*)d_in[18];
    const float* fc1b   = (const float*)d_in[19];
    const float* fc2w   = (const float*)d_in[20];
    const float* fc2b   = (const float*)d_in[21];
    const float* fc3w   = (const float*)d_in[22];
    const float* fc3b   = (const float*)d_in[23];

    const int N = in_sizes[0] / 128;
    const int E = in_sizes[1] / 2;
    const int Et = E / 3;
    const long NC = (long)N * 128;

    float* w = (float*)d_ws;
    float* xp   = w; w += (long)N * 512;    // xp16 (bf16, half) + LSTM h0/h1
    float* l1   = w; w += NC;
    float* l2   = w; w += NC;
    float* accb = w; w += NC;               // xjk
    float* outm = w; w += NC;               // GAT: CSR cnt+bucket; LSTM: c state
    ushort* xb16 = (ushort*)w; w += 3L * N * 64;   // [3][N][128] bf16 seq
    float* als  = w; w += (long)N * 4;
    float* ald  = w; w += (long)N * 4;
    float* score = w; w += 3L * N;
    ushort* gwt = (ushort*)w; w += 6 * 65536 / 2;   // bf16 GAT weights [6][512][128]
    ushort* lwt = (ushort*)w; w += 4 * 65536 / 2;   // bf16 LSTM weights (permuted)
    float* z0   = w; w += 64 * 129 + 4;

    // CSR aliases the outm region (GAT phase only); LSTM reuses outm as cbuf
    int* cnt    = (int*)outm;
    int* bucket = cnt + 3L * N;
    // xp16 uses the first half of the xp slot; h ping-pong in the second half
    ushort* xp16 = (ushort*)xp;
    ushort* h0 = xp16 + (long)N * 512;      // bytes: N*1024 + 2*N*256 <= N*2048
    ushort* h1 = h0 + NC;

    pack_gatw<<<(6 * 65536 + 255) / 256, 256, 0, stream>>>(gatW, gwt);
    pack_lstm<<<(4 * 65536 + 255) / 256, 256, 0, stream>>>(w_ih_fw, w_hh_fw, w_ih_bw, w_hh_bw, lwt);
    pack_x<<<(int)((NC / 4 + 255) / 256), 256, 0, stream>>>(x, xb16, NC);
    hipMemsetAsync(score, 0, sizeof(float) * 3 * N, stream);
    hipMemsetAsync(cnt, 0, sizeof(int) * 3 * N, stream);
    build_csr<<<(E + 255) / 256, 256, 0, stream>>>(ei, ei + E, E, Et, N, cnt, bucket);

    const int RB = (N + 127) / 128;
    const int nwg = RB * 4;
    const int ncb = (int)((NC + 255) / 256);

    // ---- GAT layers
    const float* cur = x;
    for (int p = 0; p < 2; ++p) {
        float* dstb = (p == 0) ? l1 : l2;
        ushort* d16 = xb16 + (long)(p + 1) * N * 128;
        for (int t = 0; t < 3; ++t) {
            int pt = p * 3 + t;
            gemm_att<<<nwg, 512, 0, stream>>>(cur, gwt + (long)pt * 65536, xp16,
                                              gatAs + pt * 512, gatAd + pt * 512,
                                              als, ald, N, nwg);
            gat_gather<<<(N + 3) / 4, 256, 0, stream>>>(cnt, bucket, als, ald, xp16,
                                                        gatB + pt * 128, dstb,
                                                        (t == 2) ? d16 : nullptr,
                                                        N, t, t == 0);
        }
        cur = dstb;
    }

    // ---- fused bi-LSTM via per-step dual-GEMM + cell + JK score
    float* cbuf = outm;                    // CSR dead now
    for (int dir = 0; dir < 2; ++dir) {
        const ushort* Bih = lwt + (long)(dir ? 2 : 0) * 65536;
        const ushort* Bhh = lwt + (long)(dir ? 3 : 1) * 65536;
        const float* bi = dir ? b_ih_bw : b_ih_fw;
        const float* bh = dir ? b_hh_bw : b_hh_fw;
        const float* jw = jkw + (dir ? 128 : 0);
        ushort* hp = h0;
        ushort* hc = h1;
        for (int j = 0; j < 3; ++j) {
            int l = dir ? (2 - j) : j;
            const ushort* Ab = xb16 + (long)l * N * 128;
            lstm_step<<<nwg, 512, 0, stream>>>(Ab, Bih, Bhh, hp, hc, cbuf,
                                               bi, bh, jw, score + (long)l * N,
                                               N, nwg, j == 0);
            ushort* tmp = hp; hp = hc; hc = tmp;
        }
    }

    // ---- JK softmax-weighted sum, pool, MLP
    jk_kernel<<<ncb, 256, 0, stream>>>(score, x, l1, l2, accb, N);
    init_z0<<<65, 128, 0, stream>>>(ptype, z0);
    pool2<<<(N + 63) / 64, 128, 0, stream>>>(accb, batch, z0, N);
    mlp_kernel<<<64, 128, 0, stream>>>(z0, fc1w, fc1b, fc2w, fc2b, fc3w, fc3b,
                                       (float*)d_out);
}

// Round 10
// 786.549 us; speedup vs baseline: 2.1713x; 1.0085x over previous
//
#include <hip/hip_runtime.h>
#include <cfloat>

// N=50000, C=128, H=4, HC=512, E=600000, T=3, Et=200000
// GAT(2x3) -> biLSTM JK -> pool -> MLP. GEMMs in bf16 MFMA (fp32 accum).
// R10: gat_gather = 2 dst nodes per wave (32-lane halves, DEG_CAP 31) ->
// 2x outstanding loads per wave; gemm_att reads bf16 A from xb16 (x/l1/l2
// bf16 copies already exist) -> halved A fetch, no f2bf in staging.
// LSTM phase = R8/R9 verified no-spill lstm_step skeleton.

typedef __attribute__((ext_vector_type(8))) short short8;
typedef __attribute__((ext_vector_type(4))) float f32x4;

#define DEG_CAP 31   // self-loop lane must fit 32-half; P(Poisson(4)>=31) ~ 1e-17

__device__ __forceinline__ float lrelu(float x, float s) { return x > 0.f ? x : s * x; }

__device__ __forceinline__ float sigmf(float x) {
    return __builtin_amdgcn_rcpf(1.f + __expf(-x));
}
__device__ __forceinline__ float tanhf_fast(float x) {
    x = fminf(fmaxf(x, -15.f), 15.f);
    float e = __expf(2.f * x);
    return (e - 1.f) * __builtin_amdgcn_rcpf(e + 1.f);
}

__device__ __forceinline__ unsigned f2bf(float f) {   // RNE f32->bf16 (bits)
    unsigned u = __float_as_uint(f);
    return (u + 0x7FFFu + ((u >> 16) & 1u)) >> 16;
}
__device__ __forceinline__ float bflo(unsigned u) {   // low bf16 of packed pair
    return __uint_as_float(u << 16);
}
__device__ __forceinline__ float bfhi(unsigned u) {   // high bf16 of packed pair
    return __uint_as_float(u & 0xFFFF0000u);
}

// bijective XCD-chunked swizzle (m204): consecutive tiles land on one XCD
__device__ __forceinline__ int xcd_tile(int bid, int nwg) {
    int q = nwg >> 3, r = nwg & 7;
    int xcd = bid & 7, idx = bid >> 3;
    return (xcd < r ? xcd * (q + 1) : r * (q + 1) + (xcd - r) * q) + idx;
}

// stage 128x128 bf16 A tile (row-guarded) into XOR-swizzled LDS. 512 thr.
__device__ __forceinline__ void stage_a16(
    char* ldsA, const ushort* __restrict__ A, int row0, int M, int tid)
{
#pragma unroll
    for (int it = 0; it < 4; ++it) {
        int idx = it * 512 + tid;
        int r = idx >> 4, kc = (idx & 15) << 3;
        int row = row0 + r;
        uint4 v = make_uint4(0, 0, 0, 0);
        if (row < M) v = *(const uint4*)(A + (long)row * 128 + kc);
        *(uint4*)(ldsA + ((r * 256 + kc * 2) ^ ((r & 7) << 4))) = v;
    }
}
// stage 128x128 bf16 B tile (unguarded) into XOR-swizzled LDS. 512 thr.
__device__ __forceinline__ void stage_b16(
    char* ldsB, const ushort* __restrict__ B, int tid)
{
#pragma unroll
    for (int it = 0; it < 4; ++it) {
        int idx = it * 512 + tid;
        int r = idx >> 4, kc = (idx & 15) << 3;
        *(uint4*)(ldsB + ((r * 256 + kc * 2) ^ ((r & 7) << 4))) =
            *(const uint4*)(B + (long)r * 128 + kc);
    }
}

// per-wave 32x64 MFMA tile compute (8 waves cover 128x128)
__device__ __forceinline__ void compute_tile(
    const char* ldsA, const char* ldsB, f32x4 acc[2][4],
    int wr, int wc, int lr, int lk)
{
#pragma unroll
    for (int ks = 0; ks < 4; ++ks) {
        int kb = ks * 64 + lk;
        short8 af[2], bfr[4];
#pragma unroll
        for (int i = 0; i < 2; ++i) {
            int r = wr + i * 16 + lr;
            af[i] = *(const short8*)(ldsA + ((r * 256 + kb) ^ ((r & 7) << 4)));
        }
#pragma unroll
        for (int j = 0; j < 4; ++j) {
            int c = wc + j * 16 + lr;
            bfr[j] = *(const short8*)(ldsB + ((c * 256 + kb) ^ ((c & 7) << 4)));
        }
#pragma unroll
        for (int i = 0; i < 2; ++i)
#pragma unroll
            for (int j = 0; j < 4; ++j)
                acc[i][j] = __builtin_amdgcn_mfma_f32_16x16x32_bf16(af[i], bfr[j], acc[i][j], 0, 0, 0);
    }
}

// ---------------- GAT GEMM: xp16[M,512](bf16) = A16 @ Bt^T ; fused als/ald
__global__ __launch_bounds__(512, 4) void gemm_att(
    const ushort* __restrict__ A16, const ushort* __restrict__ Bt,
    ushort* __restrict__ C16, const float* __restrict__ a_s,
    const float* __restrict__ a_d, float* __restrict__ als,
    float* __restrict__ ald, int M, int nwg)
{
    __shared__ char lds[65536];
    __shared__ float smS[128], smD[128];
    char* ldsA = lds;
    char* ldsB = lds + 32768;
    const int tid = threadIdx.x;
    int tile = xcd_tile(blockIdx.x, nwg);
    int row0 = (tile >> 2) * 128;
    int h = tile & 3;                 // col tile == head
    int col0 = h * 128;
    if (tid < 128) { smS[tid] = 0.f; smD[tid] = 0.f; }
    stage_a16(ldsA, A16, row0, M, tid);
    stage_b16(ldsB, Bt + (long)col0 * 128, tid);
    __syncthreads();

    const int wv = tid >> 6, lane = tid & 63;
    const int wr = (wv & 3) * 32, wc = (wv >> 2) * 64;
    const int lr = lane & 15;
    const int lk = (lane >> 4) << 4;
    f32x4 acc[2][4] = {};
    compute_tile(ldsA, ldsB, acc, wr, wc, lr, lk);

    const float* asl = a_s + h * 128;
    const float* adl = a_d + h * 128;
#pragma unroll
    for (int i = 0; i < 2; ++i) {
#pragma unroll
        for (int q = 0; q < 4; ++q) {
            float ps = 0.f, pd = 0.f;
            int row = row0 + wr + i * 16 + (lane >> 4) * 4 + q;
#pragma unroll
            for (int j = 0; j < 4; ++j) {
                int cc = wc + j * 16 + lr;
                float v = acc[i][j][q];
                ps += v * asl[cc];
                pd += v * adl[cc];
                if (row < M) C16[(long)row * 512 + col0 + cc] = (ushort)f2bf(v);
            }
#pragma unroll
            for (int off = 8; off; off >>= 1) {
                ps += __shfl_xor(ps, off);
                pd += __shfl_xor(pd, off);
            }
            if (lr == 0) {
                int rl = wr + i * 16 + (lane >> 4) * 4 + q;
                atomicAdd(&smS[rl], ps);
                atomicAdd(&smD[rl], pd);
            }
        }
    }
    __syncthreads();
    if (tid < 128) {
        int row = row0 + tid;
        if (row < M) {
            als[(long)row * 4 + h] = smS[tid];
            ald[(long)row * 4 + h] = smD[tid];
        }
    }
}

// ---------------- fused LSTM step: dual GEMM (ih+hh, permuted B) + cell + JK.
__global__ __launch_bounds__(512, 4) void lstm_step(
    const ushort* __restrict__ Ab, const ushort* __restrict__ Bih,
    const ushort* __restrict__ Bhh, const ushort* __restrict__ hprev,
    ushort* __restrict__ hcur, float* __restrict__ cbuf,
    const float* __restrict__ bi, const float* __restrict__ bh,
    const float* __restrict__ jw, float* __restrict__ score,
    int N, int nwg, int first)
{
    __shared__ char lds[65536];
    __shared__ float ssc[128];
    char* ldsA = lds;
    char* ldsB = lds + 32768;
    const int tid = threadIdx.x;
    int tile = xcd_tile(blockIdx.x, nwg);
    int row0 = (tile >> 2) * 128;
    int cc = tile & 3;
    if (tid < 128) ssc[tid] = 0.f;

    const int wv = tid >> 6, lane = tid & 63;
    const int wr = (wv & 3) * 32, wc = (wv >> 2) * 64;
    const int lr = lane & 15, lg = lane >> 4;
    const int lk = lg << 4;
    f32x4 acc[2][4] = {};

    // pass 1: x @ Wih[cc]
    stage_a16(ldsA, Ab, row0, N, tid);
    stage_b16(ldsB, Bih + (long)cc * 128 * 128, tid);
    __syncthreads();
    compute_tile(ldsA, ldsB, acc, wr, wc, lr, lk);
    // pass 2: hprev @ Whh[cc]
    if (!first) {
        __syncthreads();
        stage_a16(ldsA, hprev, row0, N, tid);
        stage_b16(ldsB, Bhh + (long)cc * 128 * 128, tid);
        __syncthreads();
        compute_tile(ldsA, ldsB, acc, wr, wc, lr, lk);
    }

    // epilogue: j == gate (i,f,g,o); channel = cc*32 + (wc/64)*16 + lr
    const int ch = cc * 32 + (wc >> 6) * 16 + lr;
    const float bI = bi[ch] + bh[ch];
    const float bF = bi[128 + ch] + bh[128 + ch];
    const float bG = bi[256 + ch] + bh[256 + ch];
    const float bO = bi[384 + ch] + bh[384 + ch];
    const float jv = jw[ch];
    float psum[8];
#pragma unroll
    for (int i = 0; i < 2; ++i) {
#pragma unroll
        for (int q = 0; q < 4; ++q) {
            int u = i * 4 + q;
            int row = row0 + wr + i * 16 + lg * 4 + q;
            float p = 0.f;
            if (row < N) {
                long off = (long)row * 128 + ch;
                float cprev = first ? 0.f : cbuf[off];
                float cv = sigmf(acc[i][1][q] + bF) * cprev
                         + sigmf(acc[i][0][q] + bI) * tanhf_fast(acc[i][2][q] + bG);
                float hv = sigmf(acc[i][3][q] + bO) * tanhf_fast(cv);
                cbuf[off] = cv;
                hcur[off] = (ushort)f2bf(hv);
                p = hv * jv;
            }
            psum[u] = p;
        }
    }
#pragma unroll
    for (int u = 0; u < 8; ++u) {
        float p = psum[u];
#pragma unroll
        for (int off = 8; off; off >>= 1) p += __shfl_xor(p, off);
        if (lr == 0)
            atomicAdd(&ssc[wr + (u >> 2) * 16 + lg * 4 + (u & 3)], p);
    }
    __syncthreads();
    if (tid < 128) {
        int row = row0 + tid;
        if (row < N) unsafeAtomicAdd(&score[row], ssc[tid]);
    }
}

// ---------------- weight prepack
__global__ void pack_gatw(const float* __restrict__ gw, ushort* __restrict__ out) {
    int i = blockIdx.x * 256 + threadIdx.x;
    if (i >= 6 * 65536) return;
    int pt = i >> 16, rem = i & 65535, n = rem >> 7, k = rem & 127;
    out[i] = (ushort)f2bf(gw[pt * 65536 + k * 512 + n]);
}
// LSTM weights, gate-interleaved permutation: col' -> orig row g*128+ch
__global__ void pack_lstm(const float* __restrict__ a, const float* __restrict__ b,
                          const float* __restrict__ c, const float* __restrict__ d,
                          ushort* __restrict__ out) {
    int i = blockIdx.x * 256 + threadIdx.x;
    if (i >= 4 * 65536) return;
    const float* p = (i < 65536) ? a : (i < 131072) ? b : (i < 196608) ? c : d;
    int rem = i & 65535;
    int cp = rem >> 7, k = rem & 127;
    int g = (cp >> 4) & 3;
    int ch = ((cp >> 6) << 4) | (cp & 15);
    out[i] = (ushort)f2bf(p[(g * 128 + ch) * 128 + k]);
}
// x f32 -> bf16
__global__ void pack_x(const float* __restrict__ x, ushort* __restrict__ o, long n) {
    long i = ((long)blockIdx.x * 256 + threadIdx.x) * 4;
    if (i >= n) return;
    float4 v = *(const float4*)(x + i);
    ushort4 u;
    u.x = (ushort)f2bf(v.x); u.y = (ushort)f2bf(v.y);
    u.z = (ushort)f2bf(v.z); u.w = (ushort)f2bf(v.w);
    *(ushort4*)(o + i) = u;
}

// ---------------- CSR build: bucket incoming edges by dst (per edge type)
__global__ __launch_bounds__(256) void build_csr(
    const int* __restrict__ srcs, const int* __restrict__ dsts,
    int E, int Et, int N, int* __restrict__ cnt, int* __restrict__ bucket)
{
    int i = blockIdx.x * 256 + threadIdx.x;
    if (i >= E) return;
    int t = i / Et;
    int s = srcs[i];
    int d = dsts[i];
    int slot = atomicAdd(&cnt[t * N + d], 1);
    if (slot < DEG_CAP) bucket[((long)(t * N + d)) * DEG_CAP + slot] = s;
}

// ---------------- fused GAT aggregation: TWO dst nodes per wave.
// Lanes 0-31 = node A, 32-63 = node B. Per half: edge softmax (32-wide
// shfl_xor), then gather loop to wave-max degree; padding lanes carry
// alpha=0 so excess iterations are no-ops. Lane hl owns channels
// {2(hl+32k), 2(hl+32k)+1}, k=0..3 (8 uints/row/lane -> 2x in-flight).
__global__ __launch_bounds__(256) void gat_gather(
    const int* __restrict__ cnt, const int* __restrict__ bucket,
    const float* __restrict__ als, const float* __restrict__ ald,
    const ushort* __restrict__ xp16, const float* __restrict__ bias,
    float* __restrict__ dstb, ushort* __restrict__ out16, int N, int t, int first)
{
    int lane = threadIdx.x & 63;
    int half = lane >> 5, hl = lane & 31;
    int d = blockIdx.x * 8 + (threadIdx.x >> 6) * 2 + half;
    if (d >= N) d = N - 1;            // clamp: duplicate work, single writer wins
    int deg = min(cnt[t * N + d], DEG_CAP);
    int s = d;
    if (hl < deg) s = bucket[((long)(t * N + d)) * DEG_CAP + hl];
    bool act = (hl <= deg);
    float4 ad = *(const float4*)(ald + (long)d * 4);
    float l0 = -FLT_MAX, l1 = -FLT_MAX, l2 = -FLT_MAX, l3 = -FLT_MAX;
    if (act) {
        float4 as = *(const float4*)(als + (long)s * 4);
        l0 = lrelu(as.x + ad.x, 0.2f);
        l1 = lrelu(as.y + ad.y, 0.2f);
        l2 = lrelu(as.z + ad.z, 0.2f);
        l3 = lrelu(as.w + ad.w, 0.2f);
    }
    // 32-wide max within each half (off<32 keeps lanes in-half)
    float m0 = l0, m1 = l1, m2 = l2, m3 = l3;
#pragma unroll
    for (int off = 16; off; off >>= 1) {
        m0 = fmaxf(m0, __shfl_xor(m0, off));
        m1 = fmaxf(m1, __shfl_xor(m1, off));
        m2 = fmaxf(m2, __shfl_xor(m2, off));
        m3 = fmaxf(m3, __shfl_xor(m3, off));
    }
    float e0 = 0.f, e1 = 0.f, e2 = 0.f, e3 = 0.f;
    if (act) {
        e0 = __expf(l0 - m0); e1 = __expf(l1 - m1);
        e2 = __expf(l2 - m2); e3 = __expf(l3 - m3);
    }
    float s0 = e0, s1 = e1, s2 = e2, s3 = e3;
#pragma unroll
    for (int off = 16; off; off >>= 1) {
        s0 += __shfl_xor(s0, off);
        s1 += __shfl_xor(s1, off);
        s2 += __shfl_xor(s2, off);
        s3 += __shfl_xor(s3, off);
    }
    float a0 = 0.25f * e0 / s0, a1 = 0.25f * e1 / s1;
    float a2 = 0.25f * e2 / s2, a3 = 0.25f * e3 / s3;
    // padding lanes: e*=0 -> a*=0 (zero contribution in the loop)

    // wave-max degree (both halves run the same trip count)
    int md = deg;
#pragma unroll
    for (int off = 32; off; off >>= 1) md = max(md, __shfl_xor(md, off));

    // depth-2 pipeline; row = 256 uints over 32 lanes (8 uints/lane)
    int base = (lane & 32);
    float accL[4] = {0.f, 0.f, 0.f, 0.f}, accH[4] = {0.f, 0.f, 0.f, 0.f};
    int sj = __shfl(s, base);
    const uint* xs = (const uint*)(xp16 + (long)sj * 512);
    uint c0 = xs[hl], c1 = xs[32 + hl], c2 = xs[64 + hl], c3 = xs[96 + hl];
    uint c4 = xs[128 + hl], c5 = xs[160 + hl], c6 = xs[192 + hl], c7 = xs[224 + hl];
    for (int j = 0; j < md; ++j) {
        int sn = __shfl(s, base + j + 1);
        const uint* xn = (const uint*)(xp16 + (long)sn * 512);
        uint n0 = xn[hl], n1 = xn[32 + hl], n2 = xn[64 + hl], n3 = xn[96 + hl];
        uint n4 = xn[128 + hl], n5 = xn[160 + hl], n6 = xn[192 + hl], n7 = xn[224 + hl];
        float w0 = __shfl(a0, base + j), w1 = __shfl(a1, base + j);
        float w2 = __shfl(a2, base + j), w3 = __shfl(a3, base + j);
        accL[0] += w0 * bflo(c0) + w1 * bflo(c2) + w2 * bflo(c4) + w3 * bflo(c6);
        accH[0] += w0 * bfhi(c0) + w1 * bfhi(c2) + w2 * bfhi(c4) + w3 * bfhi(c6);
        accL[1] += w0 * bflo(c1) + w1 * bflo(c3) + w2 * bflo(c5) + w3 * bflo(c7);
        accH[1] += w0 * bfhi(c1) + w1 * bfhi(c3) + w2 * bfhi(c5) + w3 * bfhi(c7);
        accL[2] += 0.f; // (kept simple: heads are at fixed 64-uint strides)
        c0 = n0; c1 = n1; c2 = n2; c3 = n3;
        c4 = n4; c5 = n5; c6 = n6; c7 = n7;
    }
    {
        float w0 = __shfl(a0, base + md), w1 = __shfl(a1, base + md);
        float w2 = __shfl(a2, base + md), w3 = __shfl(a3, base + md);
        accL[0] += w0 * bflo(c0) + w1 * bflo(c2) + w2 * bflo(c4) + w3 * bflo(c6);
        accH[0] += w0 * bfhi(c0) + w1 * bfhi(c2) + w2 * bfhi(c4) + w3 * bfhi(c6);
        accL[1] += w0 * bflo(c1) + w1 * bflo(c3) + w2 * bflo(c5) + w3 * bflo(c7);
        accH[1] += w0 * bfhi(c1) + w1 * bfhi(c3) + w2 * bfhi(c5) + w3 * bfhi(c7);
    }
    // NOTE on layout: row uints 0..63 = head0 (128 ch), 64..127 = head1, etc.
    // Lane hl reads uints {hl, 32+hl} of each head-block pair:
    //   c0=uint hl       (head0, ch 2hl,2hl+1)      -> weight a0
    //   c1=uint 32+hl    (head0, ch 64+2hl,..)      -> weight a0  [but stored
    // above with a0 via c1? c1 pairs with w0 as well -- same head0]
    // c2=uint 64+hl (head1) w1, c3=96+hl (head1) w1, c4=128+hl (head2) w2,
    // c5=160+hl (head2) w2, c6=192+hl (head3) w3, c7=224+hl (head3) w3.

    // outputs: lane owns channels 2hl..2hl+1 (accL[0],accH[0]) and
    // 64+2hl..64+2hl+1 (accL[1],accH[1])
    int chA = 2 * hl;
    int chB = 64 + 2 * hl;
    float r0 = lrelu(accL[0] + bias[chA], 0.01f) * (1.f / 3.f);
    float r1 = lrelu(accH[0] + bias[chA + 1], 0.01f) * (1.f / 3.f);
    float r2 = lrelu(accL[1] + bias[chB], 0.01f) * (1.f / 3.f);
    float r3 = lrelu(accH[1] + bias[chB + 1], 0.01f) * (1.f / 3.f);
    float2* apA = (float2*)(dstb + (long)d * 128) + hl;
    float2* apB = (float2*)(dstb + (long)d * 128 + 64) + hl;
    float2 fA, fB;
    if (first) { fA.x = r0; fA.y = r1; fB.x = r2; fB.y = r3; }
    else {
        float2 pA = *apA, pB = *apB;
        fA.x = pA.x + r0; fA.y = pA.y + r1;
        fB.x = pB.x + r2; fB.y = pB.y + r3;
    }
    *apA = fA; *apB = fB;
    if (out16) {
        ushort2 uA, uB;
        uA.x = (ushort)f2bf(fA.x); uA.y = (ushort)f2bf(fA.y);
        uB.x = (ushort)f2bf(fB.x); uB.y = (ushort)f2bf(fB.y);
        *((ushort2*)(out16 + (long)d * 128) + hl) = uA;
        *((ushort2*)(out16 + (long)d * 128 + 64) + hl) = uB;
    }
}

__global__ void jk_kernel(const float* __restrict__ score, const float* __restrict__ x0,
                          const float* __restrict__ x1, const float* __restrict__ x2,
                          float* __restrict__ xjk, int N)
{
    long i = (long)blockIdx.x * 256 + threadIdx.x;
    long n = i >> 7;
    if (n >= N) return;
    float s0 = score[n], s1 = score[N + n], s2 = score[2L * N + n];
    float m = fmaxf(s0, fmaxf(s1, s2));
    float e0 = expf(s0 - m), e1 = expf(s1 - m), e2 = expf(s2 - m);
    float inv = 1.f / (e0 + e1 + e2);
    xjk[i] = (e0 * x0[i] + e1 * x1[i] + e2 * x2[i]) * inv;
}

// z0 init: zeros + ptype in col 128
__global__ void init_z0(const float* __restrict__ ptype, float* __restrict__ z0) {
    int i = blockIdx.x * 128 + threadIdx.x;
    if (i < 64 * 129) z0[i] = ((i % 129) == 128) ? ptype[i / 129] : 0.f;
}

// parallel pool: 64-node chunks, flush on graph boundary
__global__ __launch_bounds__(128) void pool2(
    const float* __restrict__ xjk, const int* __restrict__ batch,
    float* __restrict__ z0, int N)
{
    int c = threadIdx.x;
    int n0 = blockIdx.x * 64;
    if (n0 >= N) return;
    int n1 = min(n0 + 64, N);
    float s = 0.f;
    int g = batch[n0];
    for (int n = n0; n < n1; ++n) {
        int b = batch[n];
        if (b != g) { unsafeAtomicAdd(&z0[g * 129 + c], s); s = 0.f; g = b; }
        s += xjk[(long)n * 128 + c];
    }
    unsafeAtomicAdd(&z0[g * 129 + c], s);
}

__global__ __launch_bounds__(128) void mlp_kernel(
    const float* __restrict__ z0, const float* __restrict__ w1, const float* __restrict__ b1,
    const float* __restrict__ w2, const float* __restrict__ b2,
    const float* __restrict__ w3, const float* __restrict__ b3,
    float* __restrict__ out)
{
    int gidx = blockIdx.x, tid = threadIdx.x;
    __shared__ float zin[129], z1[80], z2[80];
    zin[tid] = z0[gidx * 129 + tid];
    if (tid == 0) zin[128] = z0[gidx * 129 + 128];
    __syncthreads();
    if (tid < 80) {
        float s = b1[tid];
        for (int k = 0; k < 129; ++k) s += zin[k] * w1[k * 80 + tid];
        z1[tid] = lrelu(s, 0.01f);
    }
    __syncthreads();
    if (tid < 80) {
        float s = b2[tid];
        for (int k = 0; k < 80; ++k) s += z1[k] * w2[k * 80 + tid];
        z2[tid] = lrelu(s, 0.01f);
    }
    __syncthreads();
    if (tid < 10) {
        float s = b3[tid];
        for (int k = 0; k < 80; ++k) s += z2[k] * w3[k * 10 + tid];
        out[gidx * 10 + tid] = s;
    }
}

extern "C" void kernel_launch(void* const* d_in, const int* in_sizes, int n_in,
                              void* d_out, int out_size, void* d_ws, size_t ws_size,
                              hipStream_t stream)
{
    (void)n_in; (void)out_size; (void)ws_size;
    const float* x      = (const float*)d_in[0];
    const int*   ei     = (const int*)d_in[1];
    const int*   batch  = (const int*)d_in[2];
    const float* ptype  = (const float*)d_in[3];
    const float* gatW   = (const float*)d_in[4];
    const float* gatAs  = (const float*)d_in[5];
    const float* gatAd  = (const float*)d_in[6];
    const float* gatB   = (const float*)d_in[7];
    const float* w_ih_fw = (const float*)d_in[8];
    const float* w_hh_fw = (const float*)d_in[9];
    const float* b_ih_fw = (const float*)d_in[10];
    const float* b_hh_fw = (const float*)d_in[11];
    const float* w_ih_bw = (const float*)d_in[12];
    const float* w_hh_bw = (const float*)d_in[13];
    const float* b_ih_bw = (const float*)d_in[14];
    const float* b_hh_bw = (const float*)d_in[15];
    const float* jkw    = (const float*)d_in[16];
    const float* fc1w   = (const float*)d_in[18];
    const float* fc1b   = (const float*)d_in[19];
    const float* fc2w   = (const float*)d_in[20];
    const float* fc2b   = (const float*)d_in[21];
    const float* fc3w   = (const float*)d_in[22];
    const float* fc3b   = (const float*)d_in[23];

    const int N = in_sizes[0] / 128;
    const int E = in_sizes[1] / 2;
    const int Et = E / 3;
    const long NC = (long)N * 128;

    float* w = (float*)d_ws;
    float* xp   = w; w += (long)N * 512;    // xp16 (bf16, half) + LSTM h0/h1
    float* l1   = w; w += NC;
    float* l2   = w; w += NC;
    float* accb = w; w += NC;               // xjk
    float* outm = w; w += NC;               // GAT: CSR cnt+bucket; LSTM: c state
    ushort* xb16 = (ushort*)w; w += 3L * N * 64;   // [3][N][128] bf16 seq
    float* als  = w; w += (long)N * 4;
    float* ald  = w; w += (long)N * 4;
    float* score = w; w += 3L * N;
    ushort* gwt = (ushort*)w; w += 6 * 65536 / 2;   // bf16 GAT weights [6][512][128]
    ushort* lwt = (ushort*)w; w += 4 * 65536 / 2;   // bf16 LSTM weights (permuted)
    float* z0   = w; w += 64 * 129 + 4;

    // CSR aliases the outm region (GAT phase only); LSTM reuses outm as cbuf
    int* cnt    = (int*)outm;
    int* bucket = cnt + 3L * N;
    // xp16 uses the first half of the xp slot; h ping-pong in the second half
    ushort* xp16 = (ushort*)xp;
    ushort* h0 = xp16 + (long)N * 512;
    ushort* h1 = h0 + NC;

    pack_gatw<<<(6 * 65536 + 255) / 256, 256, 0, stream>>>(gatW, gwt);
    pack_lstm<<<(4 * 65536 + 255) / 256, 256, 0, stream>>>(w_ih_fw, w_hh_fw, w_ih_bw, w_hh_bw, lwt);
    pack_x<<<(int)((NC / 4 + 255) / 256), 256, 0, stream>>>(x, xb16, NC);
    hipMemsetAsync(score, 0, sizeof(float) * 3 * N, stream);
    hipMemsetAsync(cnt, 0, sizeof(int) * 3 * N, stream);
    build_csr<<<(E + 255) / 256, 256, 0, stream>>>(ei, ei + E, E, Et, N, cnt, bucket);

    const int RB = (N + 127) / 128;
    const int nwg = RB * 4;
    const int ncb = (int)((NC + 255) / 256);

    // ---- GAT layers (A inputs read from bf16 xb16 copies)
    for (int p = 0; p < 2; ++p) {
        const ushort* curA = xb16 + (long)p * N * 128;
        float* dstb = (p == 0) ? l1 : l2;
        ushort* d16 = xb16 + (long)(p + 1) * N * 128;
        for (int t = 0; t < 3; ++t) {
            int pt = p * 3 + t;
            gemm_att<<<nwg, 512, 0, stream>>>(curA, gwt + (long)pt * 65536, xp16,
                                              gatAs + pt * 512, gatAd + pt * 512,
                                              als, ald, N, nwg);
            gat_gather<<<(N + 7) / 8, 256, 0, stream>>>(cnt, bucket, als, ald, xp16,
                                                        gatB + pt * 128, dstb,
                                                        (t == 2) ? d16 : nullptr,
                                                        N, t, t == 0);
        }
    }

    // ---- fused bi-LSTM via per-step dual-GEMM + cell + JK score
    float* cbuf = outm;                    // CSR dead now
    for (int dir = 0; dir < 2; ++dir) {
        const ushort* Bih = lwt + (long)(dir ? 2 : 0) * 65536;
        const ushort* Bhh = lwt + (long)(dir ? 3 : 1) * 65536;
        const float* bi = dir ? b_ih_bw : b_ih_fw;
        const float* bh = dir ? b_hh_bw : b_hh_fw;
        const float* jw = jkw + (dir ? 128 : 0);
        ushort* hp = h0;
        ushort* hc = h1;
        for (int j = 0; j < 3; ++j) {
            int l = dir ? (2 - j) : j;
            const ushort* Ab = xb16 + (long)l * N * 128;
            lstm_step<<<nwg, 512, 0, stream>>>(Ab, Bih, Bhh, hp, hc, cbuf,
                                               bi, bh, jw, score + (long)l * N,
                                               N, nwg, j == 0);
            ushort* tmp = hp; hp = hc; hc = tmp;
        }
    }

    // ---- JK softmax-weighted sum, pool, MLP
    jk_kernel<<<ncb, 256, 0, stream>>>(score, x, l1, l2, accb, N);
    init_z0<<<65, 128, 0, stream>>>(ptype, z0);
    pool2<<<(N + 63) / 64, 128, 0, stream>>>(accb, batch, z0, N);
    mlp_kernel<<<64, 128, 0, stream>>>(z0, fc1w, fc1b, fc2w, fc2b, fc3w, fc3b,
                                       (float*)d_out);
}

// Round 11
// 778.214 us; speedup vs baseline: 2.1946x; 1.0107x over previous
//
#include <hip/hip_runtime.h>
#include <cfloat>

// N=50000, C=128, H=4, HC=512, E=600000, T=3, Et=200000
// GAT(2x3) -> biLSTM JK -> pool -> MLP. GEMMs in bf16 MFMA (fp32 accum).
// R11: c-state in bf16 (h already bf16); skip c/h writes on each direction's
// final step (never read); jk softmax fused into the pool kernel (xjk buffer
// eliminated). GAT phase = R10 (gather at its random-access floor).

typedef __attribute__((ext_vector_type(8))) short short8;
typedef __attribute__((ext_vector_type(4))) float f32x4;

#define DEG_CAP 31   // self-loop lane must fit 32-half; P(Poisson(4)>=31) ~ 1e-17

__device__ __forceinline__ float lrelu(float x, float s) { return x > 0.f ? x : s * x; }

__device__ __forceinline__ float sigmf(float x) {
    return __builtin_amdgcn_rcpf(1.f + __expf(-x));
}
__device__ __forceinline__ float tanhf_fast(float x) {
    x = fminf(fmaxf(x, -15.f), 15.f);
    float e = __expf(2.f * x);
    return (e - 1.f) * __builtin_amdgcn_rcpf(e + 1.f);
}

__device__ __forceinline__ unsigned f2bf(float f) {   // RNE f32->bf16 (bits)
    unsigned u = __float_as_uint(f);
    return (u + 0x7FFFu + ((u >> 16) & 1u)) >> 16;
}
__device__ __forceinline__ float bf2f(ushort u) {     // bf16 bits -> f32
    return __uint_as_float(((unsigned)u) << 16);
}
__device__ __forceinline__ float bflo(unsigned u) {   // low bf16 of packed pair
    return __uint_as_float(u << 16);
}
__device__ __forceinline__ float bfhi(unsigned u) {   // high bf16 of packed pair
    return __uint_as_float(u & 0xFFFF0000u);
}

// bijective XCD-chunked swizzle (m204): consecutive tiles land on one XCD
__device__ __forceinline__ int xcd_tile(int bid, int nwg) {
    int q = nwg >> 3, r = nwg & 7;
    int xcd = bid & 7, idx = bid >> 3;
    return (xcd < r ? xcd * (q + 1) : r * (q + 1) + (xcd - r) * q) + idx;
}

// stage 128x128 bf16 A tile (row-guarded) into XOR-swizzled LDS. 512 thr.
__device__ __forceinline__ void stage_a16(
    char* ldsA, const ushort* __restrict__ A, int row0, int M, int tid)
{
#pragma unroll
    for (int it = 0; it < 4; ++it) {
        int idx = it * 512 + tid;
        int r = idx >> 4, kc = (idx & 15) << 3;
        int row = row0 + r;
        uint4 v = make_uint4(0, 0, 0, 0);
        if (row < M) v = *(const uint4*)(A + (long)row * 128 + kc);
        *(uint4*)(ldsA + ((r * 256 + kc * 2) ^ ((r & 7) << 4))) = v;
    }
}
// stage 128x128 bf16 B tile (unguarded) into XOR-swizzled LDS. 512 thr.
__device__ __forceinline__ void stage_b16(
    char* ldsB, const ushort* __restrict__ B, int tid)
{
#pragma unroll
    for (int it = 0; it < 4; ++it) {
        int idx = it * 512 + tid;
        int r = idx >> 4, kc = (idx & 15) << 3;
        *(uint4*)(ldsB + ((r * 256 + kc * 2) ^ ((r & 7) << 4))) =
            *(const uint4*)(B + (long)r * 128 + kc);
    }
}

// per-wave 32x64 MFMA tile compute (8 waves cover 128x128)
__device__ __forceinline__ void compute_tile(
    const char* ldsA, const char* ldsB, f32x4 acc[2][4],
    int wr, int wc, int lr, int lk)
{
#pragma unroll
    for (int ks = 0; ks < 4; ++ks) {
        int kb = ks * 64 + lk;
        short8 af[2], bfr[4];
#pragma unroll
        for (int i = 0; i < 2; ++i) {
            int r = wr + i * 16 + lr;
            af[i] = *(const short8*)(ldsA + ((r * 256 + kb) ^ ((r & 7) << 4)));
        }
#pragma unroll
        for (int j = 0; j < 4; ++j) {
            int c = wc + j * 16 + lr;
            bfr[j] = *(const short8*)(ldsB + ((c * 256 + kb) ^ ((c & 7) << 4)));
        }
#pragma unroll
        for (int i = 0; i < 2; ++i)
#pragma unroll
            for (int j = 0; j < 4; ++j)
                acc[i][j] = __builtin_amdgcn_mfma_f32_16x16x32_bf16(af[i], bfr[j], acc[i][j], 0, 0, 0);
    }
}

// ---------------- GAT GEMM: xp16[M,512](bf16) = A16 @ Bt^T ; fused als/ald
__global__ __launch_bounds__(512, 4) void gemm_att(
    const ushort* __restrict__ A16, const ushort* __restrict__ Bt,
    ushort* __restrict__ C16, const float* __restrict__ a_s,
    const float* __restrict__ a_d, float* __restrict__ als,
    float* __restrict__ ald, int M, int nwg)
{
    __shared__ char lds[65536];
    __shared__ float smS[128], smD[128];
    char* ldsA = lds;
    char* ldsB = lds + 32768;
    const int tid = threadIdx.x;
    int tile = xcd_tile(blockIdx.x, nwg);
    int row0 = (tile >> 2) * 128;
    int h = tile & 3;                 // col tile == head
    int col0 = h * 128;
    if (tid < 128) { smS[tid] = 0.f; smD[tid] = 0.f; }
    stage_a16(ldsA, A16, row0, M, tid);
    stage_b16(ldsB, Bt + (long)col0 * 128, tid);
    __syncthreads();

    const int wv = tid >> 6, lane = tid & 63;
    const int wr = (wv & 3) * 32, wc = (wv >> 2) * 64;
    const int lr = lane & 15;
    const int lk = (lane >> 4) << 4;
    f32x4 acc[2][4] = {};
    compute_tile(ldsA, ldsB, acc, wr, wc, lr, lk);

    const float* asl = a_s + h * 128;
    const float* adl = a_d + h * 128;
#pragma unroll
    for (int i = 0; i < 2; ++i) {
#pragma unroll
        for (int q = 0; q < 4; ++q) {
            float ps = 0.f, pd = 0.f;
            int row = row0 + wr + i * 16 + (lane >> 4) * 4 + q;
#pragma unroll
            for (int j = 0; j < 4; ++j) {
                int cc = wc + j * 16 + lr;
                float v = acc[i][j][q];
                ps += v * asl[cc];
                pd += v * adl[cc];
                if (row < M) C16[(long)row * 512 + col0 + cc] = (ushort)f2bf(v);
            }
#pragma unroll
            for (int off = 8; off; off >>= 1) {
                ps += __shfl_xor(ps, off);
                pd += __shfl_xor(pd, off);
            }
            if (lr == 0) {
                int rl = wr + i * 16 + (lane >> 4) * 4 + q;
                atomicAdd(&smS[rl], ps);
                atomicAdd(&smD[rl], pd);
            }
        }
    }
    __syncthreads();
    if (tid < 128) {
        int row = row0 + tid;
        if (row < M) {
            als[(long)row * 4 + h] = smS[tid];
            ald[(long)row * 4 + h] = smD[tid];
        }
    }
}

// ---------------- fused LSTM step: dual GEMM (ih+hh, permuted B) + cell + JK.
// c state in bf16; c/h writes skipped on each direction's final step.
__global__ __launch_bounds__(512, 4) void lstm_step(
    const ushort* __restrict__ Ab, const ushort* __restrict__ Bih,
    const ushort* __restrict__ Bhh, const ushort* __restrict__ hprev,
    ushort* __restrict__ hcur, ushort* __restrict__ cbuf,
    const float* __restrict__ bi, const float* __restrict__ bh,
    const float* __restrict__ jw, float* __restrict__ score,
    int N, int nwg, int first, int last)
{
    __shared__ char lds[65536];
    __shared__ float ssc[128];
    char* ldsA = lds;
    char* ldsB = lds + 32768;
    const int tid = threadIdx.x;
    int tile = xcd_tile(blockIdx.x, nwg);
    int row0 = (tile >> 2) * 128;
    int cc = tile & 3;
    if (tid < 128) ssc[tid] = 0.f;

    const int wv = tid >> 6, lane = tid & 63;
    const int wr = (wv & 3) * 32, wc = (wv >> 2) * 64;
    const int lr = lane & 15, lg = lane >> 4;
    const int lk = lg << 4;
    f32x4 acc[2][4] = {};

    // pass 1: x @ Wih[cc]
    stage_a16(ldsA, Ab, row0, N, tid);
    stage_b16(ldsB, Bih + (long)cc * 128 * 128, tid);
    __syncthreads();
    compute_tile(ldsA, ldsB, acc, wr, wc, lr, lk);
    // pass 2: hprev @ Whh[cc]
    if (!first) {
        __syncthreads();
        stage_a16(ldsA, hprev, row0, N, tid);
        stage_b16(ldsB, Bhh + (long)cc * 128 * 128, tid);
        __syncthreads();
        compute_tile(ldsA, ldsB, acc, wr, wc, lr, lk);
    }

    // epilogue: j == gate (i,f,g,o); channel = cc*32 + (wc/64)*16 + lr
    const int ch = cc * 32 + (wc >> 6) * 16 + lr;
    const float bI = bi[ch] + bh[ch];
    const float bF = bi[128 + ch] + bh[128 + ch];
    const float bG = bi[256 + ch] + bh[256 + ch];
    const float bO = bi[384 + ch] + bh[384 + ch];
    const float jv = jw[ch];
    float psum[8];
#pragma unroll
    for (int i = 0; i < 2; ++i) {
#pragma unroll
        for (int q = 0; q < 4; ++q) {
            int u = i * 4 + q;
            int row = row0 + wr + i * 16 + lg * 4 + q;
            float p = 0.f;
            if (row < N) {
                long off = (long)row * 128 + ch;
                float cprev = first ? 0.f : bf2f(cbuf[off]);
                float cv = sigmf(acc[i][1][q] + bF) * cprev
                         + sigmf(acc[i][0][q] + bI) * tanhf_fast(acc[i][2][q] + bG);
                float hv = sigmf(acc[i][3][q] + bO) * tanhf_fast(cv);
                if (!last) {
                    cbuf[off] = (ushort)f2bf(cv);
                    hcur[off] = (ushort)f2bf(hv);
                }
                p = hv * jv;
            }
            psum[u] = p;
        }
    }
#pragma unroll
    for (int u = 0; u < 8; ++u) {
        float p = psum[u];
#pragma unroll
        for (int off = 8; off; off >>= 1) p += __shfl_xor(p, off);
        if (lr == 0)
            atomicAdd(&ssc[wr + (u >> 2) * 16 + lg * 4 + (u & 3)], p);
    }
    __syncthreads();
    if (tid < 128) {
        int row = row0 + tid;
        if (row < N) unsafeAtomicAdd(&score[row], ssc[tid]);
    }
}

// ---------------- weight prepack
__global__ void pack_gatw(const float* __restrict__ gw, ushort* __restrict__ out) {
    int i = blockIdx.x * 256 + threadIdx.x;
    if (i >= 6 * 65536) return;
    int pt = i >> 16, rem = i & 65535, n = rem >> 7, k = rem & 127;
    out[i] = (ushort)f2bf(gw[pt * 65536 + k * 512 + n]);
}
// LSTM weights, gate-interleaved permutation: col' -> orig row g*128+ch
__global__ void pack_lstm(const float* __restrict__ a, const float* __restrict__ b,
                          const float* __restrict__ c, const float* __restrict__ d,
                          ushort* __restrict__ out) {
    int i = blockIdx.x * 256 + threadIdx.x;
    if (i >= 4 * 65536) return;
    const float* p = (i < 65536) ? a : (i < 131072) ? b : (i < 196608) ? c : d;
    int rem = i & 65535;
    int cp = rem >> 7, k = rem & 127;
    int g = (cp >> 4) & 3;
    int ch = ((cp >> 6) << 4) | (cp & 15);
    out[i] = (ushort)f2bf(p[(g * 128 + ch) * 128 + k]);
}
// x f32 -> bf16
__global__ void pack_x(const float* __restrict__ x, ushort* __restrict__ o, long n) {
    long i = ((long)blockIdx.x * 256 + threadIdx.x) * 4;
    if (i >= n) return;
    float4 v = *(const float4*)(x + i);
    ushort4 u;
    u.x = (ushort)f2bf(v.x); u.y = (ushort)f2bf(v.y);
    u.z = (ushort)f2bf(v.z); u.w = (ushort)f2bf(v.w);
    *(ushort4*)(o + i) = u;
}

// ---------------- CSR build: bucket incoming edges by dst (per edge type)
__global__ __launch_bounds__(256) void build_csr(
    const int* __restrict__ srcs, const int* __restrict__ dsts,
    int E, int Et, int N, int* __restrict__ cnt, int* __restrict__ bucket)
{
    int i = blockIdx.x * 256 + threadIdx.x;
    if (i >= E) return;
    int t = i / Et;
    int s = srcs[i];
    int d = dsts[i];
    int slot = atomicAdd(&cnt[t * N + d], 1);
    if (slot < DEG_CAP) bucket[((long)(t * N + d)) * DEG_CAP + slot] = s;
}

// ---------------- fused GAT aggregation: TWO dst nodes per wave (R10).
__global__ __launch_bounds__(256) void gat_gather(
    const int* __restrict__ cnt, const int* __restrict__ bucket,
    const float* __restrict__ als, const float* __restrict__ ald,
    const ushort* __restrict__ xp16, const float* __restrict__ bias,
    float* __restrict__ dstb, ushort* __restrict__ out16, int N, int t, int first)
{
    int lane = threadIdx.x & 63;
    int half = lane >> 5, hl = lane & 31;
    int d = blockIdx.x * 8 + (threadIdx.x >> 6) * 2 + half;
    if (d >= N) d = N - 1;            // clamp: duplicate work, single writer wins
    int deg = min(cnt[t * N + d], DEG_CAP);
    int s = d;
    if (hl < deg) s = bucket[((long)(t * N + d)) * DEG_CAP + hl];
    bool act = (hl <= deg);
    float4 ad = *(const float4*)(ald + (long)d * 4);
    float l0 = -FLT_MAX, l1 = -FLT_MAX, l2 = -FLT_MAX, l3 = -FLT_MAX;
    if (act) {
        float4 as = *(const float4*)(als + (long)s * 4);
        l0 = lrelu(as.x + ad.x, 0.2f);
        l1 = lrelu(as.y + ad.y, 0.2f);
        l2 = lrelu(as.z + ad.z, 0.2f);
        l3 = lrelu(as.w + ad.w, 0.2f);
    }
    float m0 = l0, m1 = l1, m2 = l2, m3 = l3;
#pragma unroll
    for (int off = 16; off; off >>= 1) {
        m0 = fmaxf(m0, __shfl_xor(m0, off));
        m1 = fmaxf(m1, __shfl_xor(m1, off));
        m2 = fmaxf(m2, __shfl_xor(m2, off));
        m3 = fmaxf(m3, __shfl_xor(m3, off));
    }
    float e0 = 0.f, e1 = 0.f, e2 = 0.f, e3 = 0.f;
    if (act) {
        e0 = __expf(l0 - m0); e1 = __expf(l1 - m1);
        e2 = __expf(l2 - m2); e3 = __expf(l3 - m3);
    }
    float s0 = e0, s1 = e1, s2 = e2, s3 = e3;
#pragma unroll
    for (int off = 16; off; off >>= 1) {
        s0 += __shfl_xor(s0, off);
        s1 += __shfl_xor(s1, off);
        s2 += __shfl_xor(s2, off);
        s3 += __shfl_xor(s3, off);
    }
    float a0 = 0.25f * e0 / s0, a1 = 0.25f * e1 / s1;
    float a2 = 0.25f * e2 / s2, a3 = 0.25f * e3 / s3;

    int md = deg;
#pragma unroll
    for (int off = 32; off; off >>= 1) md = max(md, __shfl_xor(md, off));

    int base = (lane & 32);
    float accL[2] = {0.f, 0.f}, accH[2] = {0.f, 0.f};
    int sj = __shfl(s, base);
    const uint* xs = (const uint*)(xp16 + (long)sj * 512);
    uint c0 = xs[hl], c1 = xs[32 + hl], c2 = xs[64 + hl], c3 = xs[96 + hl];
    uint c4 = xs[128 + hl], c5 = xs[160 + hl], c6 = xs[192 + hl], c7 = xs[224 + hl];
    for (int j = 0; j < md; ++j) {
        int sn = __shfl(s, base + j + 1);
        const uint* xn = (const uint*)(xp16 + (long)sn * 512);
        uint n0 = xn[hl], n1 = xn[32 + hl], n2 = xn[64 + hl], n3 = xn[96 + hl];
        uint n4 = xn[128 + hl], n5 = xn[160 + hl], n6 = xn[192 + hl], n7 = xn[224 + hl];
        float w0 = __shfl(a0, base + j), w1 = __shfl(a1, base + j);
        float w2 = __shfl(a2, base + j), w3 = __shfl(a3, base + j);
        accL[0] += w0 * bflo(c0) + w1 * bflo(c2) + w2 * bflo(c4) + w3 * bflo(c6);
        accH[0] += w0 * bfhi(c0) + w1 * bfhi(c2) + w2 * bfhi(c4) + w3 * bfhi(c6);
        accL[1] += w0 * bflo(c1) + w1 * bflo(c3) + w2 * bflo(c5) + w3 * bflo(c7);
        accH[1] += w0 * bfhi(c1) + w1 * bfhi(c3) + w2 * bfhi(c5) + w3 * bfhi(c7);
        c0 = n0; c1 = n1; c2 = n2; c3 = n3;
        c4 = n4; c5 = n5; c6 = n6; c7 = n7;
    }
    {
        float w0 = __shfl(a0, base + md), w1 = __shfl(a1, base + md);
        float w2 = __shfl(a2, base + md), w3 = __shfl(a3, base + md);
        accL[0] += w0 * bflo(c0) + w1 * bflo(c2) + w2 * bflo(c4) + w3 * bflo(c6);
        accH[0] += w0 * bfhi(c0) + w1 * bfhi(c2) + w2 * bfhi(c4) + w3 * bfhi(c6);
        accL[1] += w0 * bflo(c1) + w1 * bflo(c3) + w2 * bflo(c5) + w3 * bflo(c7);
        accH[1] += w0 * bfhi(c1) + w1 * bfhi(c3) + w2 * bfhi(c5) + w3 * bfhi(c7);
    }
    // lane hl owns channels {2hl, 2hl+1} (head-pair L) and {64+2hl, 64+2hl+1}

    int chA = 2 * hl;
    int chB = 64 + 2 * hl;
    float r0 = lrelu(accL[0] + bias[chA], 0.01f) * (1.f / 3.f);
    float r1 = lrelu(accH[0] + bias[chA + 1], 0.01f) * (1.f / 3.f);
    float r2 = lrelu(accL[1] + bias[chB], 0.01f) * (1.f / 3.f);
    float r3 = lrelu(accH[1] + bias[chB + 1], 0.01f) * (1.f / 3.f);
    float2* apA = (float2*)(dstb + (long)d * 128) + hl;
    float2* apB = (float2*)(dstb + (long)d * 128 + 64) + hl;
    float2 fA, fB;
    if (first) { fA.x = r0; fA.y = r1; fB.x = r2; fB.y = r3; }
    else {
        float2 pA = *apA, pB = *apB;
        fA.x = pA.x + r0; fA.y = pA.y + r1;
        fB.x = pB.x + r2; fB.y = pB.y + r3;
    }
    *apA = fA; *apB = fB;
    if (out16) {
        ushort2 uA, uB;
        uA.x = (ushort)f2bf(fA.x); uA.y = (ushort)f2bf(fA.y);
        uB.x = (ushort)f2bf(fB.x); uB.y = (ushort)f2bf(fB.y);
        *((ushort2*)(out16 + (long)d * 128) + hl) = uA;
        *((ushort2*)(out16 + (long)d * 128 + 64) + hl) = uB;
    }
}

// z0 init: zeros + ptype in col 128
__global__ void init_z0(const float* __restrict__ ptype, float* __restrict__ z0) {
    int i = blockIdx.x * 128 + threadIdx.x;
    if (i < 64 * 129) z0[i] = ((i % 129) == 128) ? ptype[i / 129] : 0.f;
}

// fused JK softmax + pool: per node compute 3-way softmax over scores,
// weighted-sum x/l1/l2 inline, accumulate into z0 (64-node chunks, flush
// on graph boundary). xjk buffer eliminated.
__global__ __launch_bounds__(128) void pool_jk(
    const float* __restrict__ score, const float* __restrict__ x0,
    const float* __restrict__ x1, const float* __restrict__ x2,
    const int* __restrict__ batch, float* __restrict__ z0, int N)
{
    int c = threadIdx.x;
    int n0 = blockIdx.x * 64;
    if (n0 >= N) return;
    int n1 = min(n0 + 64, N);
    float s = 0.f;
    int g = batch[n0];
    for (int n = n0; n < n1; ++n) {
        int b = batch[n];
        if (b != g) { unsafeAtomicAdd(&z0[g * 129 + c], s); s = 0.f; g = b; }
        float s0 = score[n], s1 = score[N + n], s2 = score[2L * N + n];
        float m = fmaxf(s0, fmaxf(s1, s2));
        float e0 = __expf(s0 - m), e1 = __expf(s1 - m), e2 = __expf(s2 - m);
        float inv = __builtin_amdgcn_rcpf(e0 + e1 + e2);
        long i = (long)n * 128 + c;
        s += (e0 * x0[i] + e1 * x1[i] + e2 * x2[i]) * inv;
    }
    unsafeAtomicAdd(&z0[g * 129 + c], s);
}

__global__ __launch_bounds__(128) void mlp_kernel(
    const float* __restrict__ z0, const float* __restrict__ w1, const float* __restrict__ b1,
    const float* __restrict__ w2, const float* __restrict__ b2,
    const float* __restrict__ w3, const float* __restrict__ b3,
    float* __restrict__ out)
{
    int gidx = blockIdx.x, tid = threadIdx.x;
    __shared__ float zin[129], z1[80], z2[80];
    zin[tid] = z0[gidx * 129 + tid];
    if (tid == 0) zin[128] = z0[gidx * 129 + 128];
    __syncthreads();
    if (tid < 80) {
        float s = b1[tid];
        for (int k = 0; k < 129; ++k) s += zin[k] * w1[k * 80 + tid];
        z1[tid] = lrelu(s, 0.01f);
    }
    __syncthreads();
    if (tid < 80) {
        float s = b2[tid];
        for (int k = 0; k < 80; ++k) s += z1[k] * w2[k * 80 + tid];
        z2[tid] = lrelu(s, 0.01f);
    }
    __syncthreads();
    if (tid < 10) {
        float s = b3[tid];
        for (int k = 0; k < 80; ++k) s += z2[k] * w3[k * 10 + tid];
        out[gidx * 10 + tid] = s;
    }
}

extern "C" void kernel_launch(void* const* d_in, const int* in_sizes, int n_in,
                              void* d_out, int out_size, void* d_ws, size_t ws_size,
                              hipStream_t stream)
{
    (void)n_in; (void)out_size; (void)ws_size;
    const float* x      = (const float*)d_in[0];
    const int*   ei     = (const int*)d_in[1];
    const int*   batch  = (const int*)d_in[2];
    const float* ptype  = (const float*)d_in[3];
    const float* gatW   = (const float*)d_in[4];
    const float* gatAs  = (const float*)d_in[5];
    const float* gatAd  = (const float*)d_in[6];
    const float* gatB   = (const float*)d_in[7];
    const float* w_ih_fw = (const float*)d_in[8];
    const float* w_hh_fw = (const float*)d_in[9];
    const float* b_ih_fw = (const float*)d_in[10];
    const float* b_hh_fw = (const float*)d_in[11];
    const float* w_ih_bw = (const float*)d_in[12];
    const float* w_hh_bw = (const float*)d_in[13];
    const float* b_ih_bw = (const float*)d_in[14];
    const float* b_hh_bw = (const float*)d_in[15];
    const float* jkw    = (const float*)d_in[16];
    const float* fc1w   = (const float*)d_in[18];
    const float* fc1b   = (const float*)d_in[19];
    const float* fc2w   = (const float*)d_in[20];
    const float* fc2b   = (const float*)d_in[21];
    const float* fc3w   = (const float*)d_in[22];
    const float* fc3b   = (const float*)d_in[23];

    const int N = in_sizes[0] / 128;
    const int E = in_sizes[1] / 2;
    const int Et = E / 3;
    const long NC = (long)N * 128;

    float* w = (float*)d_ws;
    float* xp   = w; w += (long)N * 512;    // xp16 (bf16, half) + LSTM h0/h1
    float* l1   = w; w += NC;
    float* l2   = w; w += NC;
    float* accb = w; w += NC;               // (unused; layout stability)
    float* outm = w; w += NC;               // GAT: CSR cnt+bucket; LSTM: c bf16
    ushort* xb16 = (ushort*)w; w += 3L * N * 64;   // [3][N][128] bf16 seq
    float* als  = w; w += (long)N * 4;
    float* ald  = w; w += (long)N * 4;
    float* score = w; w += 3L * N;
    ushort* gwt = (ushort*)w; w += 6 * 65536 / 2;   // bf16 GAT weights [6][512][128]
    ushort* lwt = (ushort*)w; w += 4 * 65536 / 2;   // bf16 LSTM weights (permuted)
    float* z0   = w; w += 64 * 129 + 4;

    // CSR aliases the outm region (GAT phase only); LSTM reuses outm as cbuf
    int* cnt    = (int*)outm;
    int* bucket = cnt + 3L * N;
    // xp16 uses the first half of the xp slot; h ping-pong in the second half
    ushort* xp16 = (ushort*)xp;
    ushort* h0 = xp16 + (long)N * 512;
    ushort* h1 = h0 + NC;

    pack_gatw<<<(6 * 65536 + 255) / 256, 256, 0, stream>>>(gatW, gwt);
    pack_lstm<<<(4 * 65536 + 255) / 256, 256, 0, stream>>>(w_ih_fw, w_hh_fw, w_ih_bw, w_hh_bw, lwt);
    pack_x<<<(int)((NC / 4 + 255) / 256), 256, 0, stream>>>(x, xb16, NC);
    hipMemsetAsync(score, 0, sizeof(float) * 3 * N, stream);
    hipMemsetAsync(cnt, 0, sizeof(int) * 3 * N, stream);
    build_csr<<<(E + 255) / 256, 256, 0, stream>>>(ei, ei + E, E, Et, N, cnt, bucket);

    const int RB = (N + 127) / 128;
    const int nwg = RB * 4;

    // ---- GAT layers (A inputs read from bf16 xb16 copies)
    for (int p = 0; p < 2; ++p) {
        const ushort* curA = xb16 + (long)p * N * 128;
        float* dstb = (p == 0) ? l1 : l2;
        ushort* d16 = xb16 + (long)(p + 1) * N * 128;
        for (int t = 0; t < 3; ++t) {
            int pt = p * 3 + t;
            gemm_att<<<nwg, 512, 0, stream>>>(curA, gwt + (long)pt * 65536, xp16,
                                              gatAs + pt * 512, gatAd + pt * 512,
                                              als, ald, N, nwg);
            gat_gather<<<(N + 7) / 8, 256, 0, stream>>>(cnt, bucket, als, ald, xp16,
                                                        gatB + pt * 128, dstb,
                                                        (t == 2) ? d16 : nullptr,
                                                        N, t, t == 0);
        }
    }

    // ---- fused bi-LSTM via per-step dual-GEMM + cell + JK score
    ushort* cbuf = (ushort*)outm;          // CSR dead now; c stored bf16
    for (int dir = 0; dir < 2; ++dir) {
        const ushort* Bih = lwt + (long)(dir ? 2 : 0) * 65536;
        const ushort* Bhh = lwt + (long)(dir ? 3 : 1) * 65536;
        const float* bi = dir ? b_ih_bw : b_ih_fw;
        const float* bh = dir ? b_hh_bw : b_hh_fw;
        const float* jw = jkw + (dir ? 128 : 0);
        ushort* hp = h0;
        ushort* hc = h1;
        for (int j = 0; j < 3; ++j) {
            int l = dir ? (2 - j) : j;
            const ushort* Ab = xb16 + (long)l * N * 128;
            lstm_step<<<nwg, 512, 0, stream>>>(Ab, Bih, Bhh, hp, hc, cbuf,
                                               bi, bh, jw, score + (long)l * N,
                                               N, nwg, j == 0, j == 2);
            ushort* tmp = hp; hp = hc; hc = tmp;
        }
    }

    // ---- fused JK softmax + pool, then MLP
    init_z0<<<65, 128, 0, stream>>>(ptype, z0);
    pool_jk<<<(N + 63) / 64, 128, 0, stream>>>(score, x, l1, l2, batch, z0, N);
    mlp_kernel<<<64, 128, 0, stream>>>(z0, fc1w, fc1b, fc2w, fc2b, fc3w, fc3b,
                                       (float*)d_out);
}

// Round 12
// 723.484 us; speedup vs baseline: 2.3606x; 1.0756x over previous
//
#include <hip/hip_runtime.h>
#include <cfloat>

// N=50000, C=128, H=4, HC=512, E=600000, T=3, Et=200000
// GAT(2x3) -> biLSTM JK -> pool -> MLP. GEMMs in bf16 MFMA (fp32 accum).
// R12: staging via __builtin_amdgcn_global_load_lds (width=16, pre-swizzled
// global source + linear LDS dest, rule #21) in gemm_att + lstm; fw/bw LSTM
// directions merged into one launch (grid (nwg,2), per-dir c + h buffers)
// -> 3 lstm launches with 2x blocks in flight. Gather = R10 (at floor).

typedef __attribute__((ext_vector_type(8))) short short8;
typedef __attribute__((ext_vector_type(4))) float f32x4;

#define DEG_CAP 31   // self-loop lane must fit 32-half; P(Poisson(4)>=31) ~ 1e-17

__device__ __forceinline__ float lrelu(float x, float s) { return x > 0.f ? x : s * x; }

__device__ __forceinline__ float sigmf(float x) {
    return __builtin_amdgcn_rcpf(1.f + __expf(-x));
}
__device__ __forceinline__ float tanhf_fast(float x) {
    x = fminf(fmaxf(x, -15.f), 15.f);
    float e = __expf(2.f * x);
    return (e - 1.f) * __builtin_amdgcn_rcpf(e + 1.f);
}

__device__ __forceinline__ unsigned f2bf(float f) {   // RNE f32->bf16 (bits)
    unsigned u = __float_as_uint(f);
    return (u + 0x7FFFu + ((u >> 16) & 1u)) >> 16;
}
__device__ __forceinline__ float bf2f(ushort u) {     // bf16 bits -> f32
    return __uint_as_float(((unsigned)u) << 16);
}
__device__ __forceinline__ float bflo(unsigned u) {   // low bf16 of packed pair
    return __uint_as_float(u << 16);
}
__device__ __forceinline__ float bfhi(unsigned u) {   // high bf16 of packed pair
    return __uint_as_float(u & 0xFFFF0000u);
}

// bijective XCD-chunked swizzle (m204): consecutive tiles land on one XCD
__device__ __forceinline__ int xcd_tile(int bid, int nwg) {
    int q = nwg >> 3, r = nwg & 7;
    int xcd = bid & 7, idx = bid >> 3;
    return (xcd < r ? xcd * (q + 1) : r * (q + 1) + (xcd - r) * q) + idx;
}

// ---- async staging: global_load_lds width=16, LINEAR LDS dest, source
// pre-swizzled so that swizzled ds_reads see logical layout (rule #21).
// LDS byte d holds logical (r = d>>8, colbyte = (d&255)^((r&7)<<4)).
__device__ __forceinline__ void stage_a_glds(
    char* ldsA, const ushort* __restrict__ A, int row0, int M, int tid)
{
    int wv = tid >> 6, lane = tid & 63;
#pragma unroll
    for (int it = 0; it < 4; ++it) {
        int chunk = it * 8 + wv;            // 32 x 1KB chunks
        int d = chunk * 1024 + lane * 16;
        int r = d >> 8;
        int col = (d & 255) ^ ((r & 7) << 4);
        int row = min(row0 + r, M - 1);     // clamp: garbage rows guarded at store
        const char* src = (const char*)A + (long)row * 256 + col;
        __builtin_amdgcn_global_load_lds(
            (const __attribute__((address_space(1))) void*)src,
            (__attribute__((address_space(3))) void*)(ldsA + chunk * 1024),
            16, 0, 0);
    }
}
__device__ __forceinline__ void stage_b_glds(
    char* ldsB, const ushort* __restrict__ B, int tid)
{
    int wv = tid >> 6, lane = tid & 63;
#pragma unroll
    for (int it = 0; it < 4; ++it) {
        int chunk = it * 8 + wv;
        int d = chunk * 1024 + lane * 16;
        int r = d >> 8;
        int col = (d & 255) ^ ((r & 7) << 4);
        const char* src = (const char*)B + (long)r * 256 + col;
        __builtin_amdgcn_global_load_lds(
            (const __attribute__((address_space(1))) void*)src,
            (__attribute__((address_space(3))) void*)(ldsB + chunk * 1024),
            16, 0, 0);
    }
}

// per-wave 32x64 MFMA tile compute (8 waves cover 128x128)
__device__ __forceinline__ void compute_tile(
    const char* ldsA, const char* ldsB, f32x4 acc[2][4],
    int wr, int wc, int lr, int lk)
{
#pragma unroll
    for (int ks = 0; ks < 4; ++ks) {
        int kb = ks * 64 + lk;
        short8 af[2], bfr[4];
#pragma unroll
        for (int i = 0; i < 2; ++i) {
            int r = wr + i * 16 + lr;
            af[i] = *(const short8*)(ldsA + ((r * 256 + kb) ^ ((r & 7) << 4)));
        }
#pragma unroll
        for (int j = 0; j < 4; ++j) {
            int c = wc + j * 16 + lr;
            bfr[j] = *(const short8*)(ldsB + ((c * 256 + kb) ^ ((c & 7) << 4)));
        }
#pragma unroll
        for (int i = 0; i < 2; ++i)
#pragma unroll
            for (int j = 0; j < 4; ++j)
                acc[i][j] = __builtin_amdgcn_mfma_f32_16x16x32_bf16(af[i], bfr[j], acc[i][j], 0, 0, 0);
    }
}

// ---------------- GAT GEMM: xp16[M,512](bf16) = A16 @ Bt^T ; fused als/ald
__global__ __launch_bounds__(512, 4) void gemm_att(
    const ushort* __restrict__ A16, const ushort* __restrict__ Bt,
    ushort* __restrict__ C16, const float* __restrict__ a_s,
    const float* __restrict__ a_d, float* __restrict__ als,
    float* __restrict__ ald, int M, int nwg)
{
    __shared__ char lds[65536];
    __shared__ float smS[128], smD[128];
    char* ldsA = lds;
    char* ldsB = lds + 32768;
    const int tid = threadIdx.x;
    int tile = xcd_tile(blockIdx.x, nwg);
    int row0 = (tile >> 2) * 128;
    int h = tile & 3;                 // col tile == head
    int col0 = h * 128;
    if (tid < 128) { smS[tid] = 0.f; smD[tid] = 0.f; }
    stage_a_glds(ldsA, A16, row0, M, tid);
    stage_b_glds(ldsB, Bt + (long)col0 * 128, tid);
    __syncthreads();

    const int wv = tid >> 6, lane = tid & 63;
    const int wr = (wv & 3) * 32, wc = (wv >> 2) * 64;
    const int lr = lane & 15;
    const int lk = (lane >> 4) << 4;
    f32x4 acc[2][4] = {};
    compute_tile(ldsA, ldsB, acc, wr, wc, lr, lk);

    const float* asl = a_s + h * 128;
    const float* adl = a_d + h * 128;
#pragma unroll
    for (int i = 0; i < 2; ++i) {
#pragma unroll
        for (int q = 0; q < 4; ++q) {
            float ps = 0.f, pd = 0.f;
            int row = row0 + wr + i * 16 + (lane >> 4) * 4 + q;
#pragma unroll
            for (int j = 0; j < 4; ++j) {
                int cc = wc + j * 16 + lr;
                float v = acc[i][j][q];
                ps += v * asl[cc];
                pd += v * adl[cc];
                if (row < M) C16[(long)row * 512 + col0 + cc] = (ushort)f2bf(v);
            }
#pragma unroll
            for (int off = 8; off; off >>= 1) {
                ps += __shfl_xor(ps, off);
                pd += __shfl_xor(pd, off);
            }
            if (lr == 0) {
                int rl = wr + i * 16 + (lane >> 4) * 4 + q;
                atomicAdd(&smS[rl], ps);
                atomicAdd(&smD[rl], pd);
            }
        }
    }
    __syncthreads();
    if (tid < 128) {
        int row = row0 + tid;
        if (row < M) {
            als[(long)row * 4 + h] = smS[tid];
            ald[(long)row * 4 + h] = smD[tid];
        }
    }
}

// ---------------- fused LSTM step, BOTH directions (blockIdx.y = dir).
// Per-dir c (bf16) + h ping-pong buffers; gate-interleaved weights; cell +
// JK score in epilogue; c/h writes skipped on last step.
__global__ __launch_bounds__(512, 4) void lstm_both(
    const ushort* __restrict__ xb, const ushort* __restrict__ lwt,
    ushort* __restrict__ hbase, ushort* __restrict__ cbase,
    const float* __restrict__ bihf, const float* __restrict__ bhhf,
    const float* __restrict__ bihb, const float* __restrict__ bhhb,
    const float* __restrict__ jkw, float* __restrict__ score,
    int N, int nwg, int jstep)
{
    __shared__ char lds[65536];
    __shared__ float ssc[128];
    char* ldsA = lds;
    char* ldsB = lds + 32768;
    const int tid = threadIdx.x;
    const int dir = blockIdx.y;
    int tile = xcd_tile(blockIdx.x, nwg);
    int row0 = (tile >> 2) * 128;
    int cc = tile & 3;
    if (tid < 128) ssc[tid] = 0.f;

    const int l = dir ? (2 - jstep) : jstep;
    const int first = (jstep == 0), last = (jstep == 2);
    const ushort* Ab = xb + (long)l * N * 128;
    const ushort* Bih = lwt + (long)dir * 2 * 65536;
    const ushort* Bhh = Bih + 65536;
    const ushort* hprev = hbase + (long)((dir << 1) | ((jstep + 1) & 1)) * N * 128;
    ushort* hcur = hbase + (long)((dir << 1) | (jstep & 1)) * N * 128;
    ushort* cbuf = cbase + (long)dir * N * 128;
    const float* bi = dir ? bihb : bihf;
    const float* bh = dir ? bhhb : bhhf;
    const float* jw = jkw + (dir ? 128 : 0);
    float* sc = score + (long)l * N;

    const int wv = tid >> 6, lane = tid & 63;
    const int wr = (wv & 3) * 32, wc = (wv >> 2) * 64;
    const int lr = lane & 15, lg = lane >> 4;
    const int lk = lg << 4;
    f32x4 acc[2][4] = {};

    // pass 1: x @ Wih[cc]
    stage_a_glds(ldsA, Ab, row0, N, tid);
    stage_b_glds(ldsB, Bih + (long)cc * 128 * 128, tid);
    __syncthreads();
    compute_tile(ldsA, ldsB, acc, wr, wc, lr, lk);
    // pass 2: hprev @ Whh[cc]
    if (!first) {
        __syncthreads();
        stage_a_glds(ldsA, hprev, row0, N, tid);
        stage_b_glds(ldsB, Bhh + (long)cc * 128 * 128, tid);
        __syncthreads();
        compute_tile(ldsA, ldsB, acc, wr, wc, lr, lk);
    }

    // epilogue: j == gate (i,f,g,o); channel = cc*32 + (wc/64)*16 + lr
    const int ch = cc * 32 + (wc >> 6) * 16 + lr;
    const float bI = bi[ch] + bh[ch];
    const float bF = bi[128 + ch] + bh[128 + ch];
    const float bG = bi[256 + ch] + bh[256 + ch];
    const float bO = bi[384 + ch] + bh[384 + ch];
    const float jv = jw[ch];
    float psum[8];
#pragma unroll
    for (int i = 0; i < 2; ++i) {
#pragma unroll
        for (int q = 0; q < 4; ++q) {
            int u = i * 4 + q;
            int row = row0 + wr + i * 16 + lg * 4 + q;
            float p = 0.f;
            if (row < N) {
                long off = (long)row * 128 + ch;
                float cprev = first ? 0.f : bf2f(cbuf[off]);
                float cv = sigmf(acc[i][1][q] + bF) * cprev
                         + sigmf(acc[i][0][q] + bI) * tanhf_fast(acc[i][2][q] + bG);
                float hv = sigmf(acc[i][3][q] + bO) * tanhf_fast(cv);
                if (!last) {
                    cbuf[off] = (ushort)f2bf(cv);
                    hcur[off] = (ushort)f2bf(hv);
                }
                p = hv * jv;
            }
            psum[u] = p;
        }
    }
#pragma unroll
    for (int u = 0; u < 8; ++u) {
        float p = psum[u];
#pragma unroll
        for (int off = 8; off; off >>= 1) p += __shfl_xor(p, off);
        if (lr == 0)
            atomicAdd(&ssc[wr + (u >> 2) * 16 + lg * 4 + (u & 3)], p);
    }
    __syncthreads();
    if (tid < 128) {
        int row = row0 + tid;
        if (row < N) unsafeAtomicAdd(&sc[row], ssc[tid]);
    }
}

// ---------------- weight prepack
__global__ void pack_gatw(const float* __restrict__ gw, ushort* __restrict__ out) {
    int i = blockIdx.x * 256 + threadIdx.x;
    if (i >= 6 * 65536) return;
    int pt = i >> 16, rem = i & 65535, n = rem >> 7, k = rem & 127;
    out[i] = (ushort)f2bf(gw[pt * 65536 + k * 512 + n]);
}
// LSTM weights, gate-interleaved permutation: col' -> orig row g*128+ch
__global__ void pack_lstm(const float* __restrict__ a, const float* __restrict__ b,
                          const float* __restrict__ c, const float* __restrict__ d,
                          ushort* __restrict__ out) {
    int i = blockIdx.x * 256 + threadIdx.x;
    if (i >= 4 * 65536) return;
    const float* p = (i < 65536) ? a : (i < 131072) ? b : (i < 196608) ? c : d;
    int rem = i & 65535;
    int cp = rem >> 7, k = rem & 127;
    int g = (cp >> 4) & 3;
    int ch = ((cp >> 6) << 4) | (cp & 15);
    out[i] = (ushort)f2bf(p[(g * 128 + ch) * 128 + k]);
}
// x f32 -> bf16
__global__ void pack_x(const float* __restrict__ x, ushort* __restrict__ o, long n) {
    long i = ((long)blockIdx.x * 256 + threadIdx.x) * 4;
    if (i >= n) return;
    float4 v = *(const float4*)(x + i);
    ushort4 u;
    u.x = (ushort)f2bf(v.x); u.y = (ushort)f2bf(v.y);
    u.z = (ushort)f2bf(v.z); u.w = (ushort)f2bf(v.w);
    *(ushort4*)(o + i) = u;
}

// ---------------- CSR build: bucket incoming edges by dst (per edge type)
__global__ __launch_bounds__(256) void build_csr(
    const int* __restrict__ srcs, const int* __restrict__ dsts,
    int E, int Et, int N, int* __restrict__ cnt, int* __restrict__ bucket)
{
    int i = blockIdx.x * 256 + threadIdx.x;
    if (i >= E) return;
    int t = i / Et;
    int s = srcs[i];
    int d = dsts[i];
    int slot = atomicAdd(&cnt[t * N + d], 1);
    if (slot < DEG_CAP) bucket[((long)(t * N + d)) * DEG_CAP + slot] = s;
}

// ---------------- fused GAT aggregation: TWO dst nodes per wave (R10).
__global__ __launch_bounds__(256) void gat_gather(
    const int* __restrict__ cnt, const int* __restrict__ bucket,
    const float* __restrict__ als, const float* __restrict__ ald,
    const ushort* __restrict__ xp16, const float* __restrict__ bias,
    float* __restrict__ dstb, ushort* __restrict__ out16, int N, int t, int first)
{
    int lane = threadIdx.x & 63;
    int half = lane >> 5, hl = lane & 31;
    int d = blockIdx.x * 8 + (threadIdx.x >> 6) * 2 + half;
    if (d >= N) d = N - 1;            // clamp: duplicate work, single writer wins
    int deg = min(cnt[t * N + d], DEG_CAP);
    int s = d;
    if (hl < deg) s = bucket[((long)(t * N + d)) * DEG_CAP + hl];
    bool act = (hl <= deg);
    float4 ad = *(const float4*)(ald + (long)d * 4);
    float l0 = -FLT_MAX, l1 = -FLT_MAX, l2 = -FLT_MAX, l3 = -FLT_MAX;
    if (act) {
        float4 as = *(const float4*)(als + (long)s * 4);
        l0 = lrelu(as.x + ad.x, 0.2f);
        l1 = lrelu(as.y + ad.y, 0.2f);
        l2 = lrelu(as.z + ad.z, 0.2f);
        l3 = lrelu(as.w + ad.w, 0.2f);
    }
    float m0 = l0, m1 = l1, m2 = l2, m3 = l3;
#pragma unroll
    for (int off = 16; off; off >>= 1) {
        m0 = fmaxf(m0, __shfl_xor(m0, off));
        m1 = fmaxf(m1, __shfl_xor(m1, off));
        m2 = fmaxf(m2, __shfl_xor(m2, off));
        m3 = fmaxf(m3, __shfl_xor(m3, off));
    }
    float e0 = 0.f, e1 = 0.f, e2 = 0.f, e3 = 0.f;
    if (act) {
        e0 = __expf(l0 - m0); e1 = __expf(l1 - m1);
        e2 = __expf(l2 - m2); e3 = __expf(l3 - m3);
    }
    float s0 = e0, s1 = e1, s2 = e2, s3 = e3;
#pragma unroll
    for (int off = 16; off; off >>= 1) {
        s0 += __shfl_xor(s0, off);
        s1 += __shfl_xor(s1, off);
        s2 += __shfl_xor(s2, off);
        s3 += __shfl_xor(s3, off);
    }
    float a0 = 0.25f * e0 / s0, a1 = 0.25f * e1 / s1;
    float a2 = 0.25f * e2 / s2, a3 = 0.25f * e3 / s3;

    int md = deg;
#pragma unroll
    for (int off = 32; off; off >>= 1) md = max(md, __shfl_xor(md, off));

    int base = (lane & 32);
    float accL[2] = {0.f, 0.f}, accH[2] = {0.f, 0.f};
    int sj = __shfl(s, base);
    const uint* xs = (const uint*)(xp16 + (long)sj * 512);
    uint c0 = xs[hl], c1 = xs[32 + hl], c2 = xs[64 + hl], c3 = xs[96 + hl];
    uint c4 = xs[128 + hl], c5 = xs[160 + hl], c6 = xs[192 + hl], c7 = xs[224 + hl];
    for (int j = 0; j < md; ++j) {
        int sn = __shfl(s, base + j + 1);
        const uint* xn = (const uint*)(xp16 + (long)sn * 512);
        uint n0 = xn[hl], n1 = xn[32 + hl], n2 = xn[64 + hl], n3 = xn[96 + hl];
        uint n4 = xn[128 + hl], n5 = xn[160 + hl], n6 = xn[192 + hl], n7 = xn[224 + hl];
        float w0 = __shfl(a0, base + j), w1 = __shfl(a1, base + j);
        float w2 = __shfl(a2, base + j), w3 = __shfl(a3, base + j);
        accL[0] += w0 * bflo(c0) + w1 * bflo(c2) + w2 * bflo(c4) + w3 * bflo(c6);
        accH[0] += w0 * bfhi(c0) + w1 * bfhi(c2) + w2 * bfhi(c4) + w3 * bfhi(c6);
        accL[1] += w0 * bflo(c1) + w1 * bflo(c3) + w2 * bflo(c5) + w3 * bflo(c7);
        accH[1] += w0 * bfhi(c1) + w1 * bfhi(c3) + w2 * bfhi(c5) + w3 * bfhi(c7);
        c0 = n0; c1 = n1; c2 = n2; c3 = n3;
        c4 = n4; c5 = n5; c6 = n6; c7 = n7;
    }
    {
        float w0 = __shfl(a0, base + md), w1 = __shfl(a1, base + md);
        float w2 = __shfl(a2, base + md), w3 = __shfl(a3, base + md);
        accL[0] += w0 * bflo(c0) + w1 * bflo(c2) + w2 * bflo(c4) + w3 * bflo(c6);
        accH[0] += w0 * bfhi(c0) + w1 * bfhi(c2) + w2 * bfhi(c4) + w3 * bfhi(c6);
        accL[1] += w0 * bflo(c1) + w1 * bflo(c3) + w2 * bflo(c5) + w3 * bflo(c7);
        accH[1] += w0 * bfhi(c1) + w1 * bfhi(c3) + w2 * bfhi(c5) + w3 * bfhi(c7);
    }

    int chA = 2 * hl;
    int chB = 64 + 2 * hl;
    float r0 = lrelu(accL[0] + bias[chA], 0.01f) * (1.f / 3.f);
    float r1 = lrelu(accH[0] + bias[chA + 1], 0.01f) * (1.f / 3.f);
    float r2 = lrelu(accL[1] + bias[chB], 0.01f) * (1.f / 3.f);
    float r3 = lrelu(accH[1] + bias[chB + 1], 0.01f) * (1.f / 3.f);
    float2* apA = (float2*)(dstb + (long)d * 128) + hl;
    float2* apB = (float2*)(dstb + (long)d * 128 + 64) + hl;
    float2 fA, fB;
    if (first) { fA.x = r0; fA.y = r1; fB.x = r2; fB.y = r3; }
    else {
        float2 pA = *apA, pB = *apB;
        fA.x = pA.x + r0; fA.y = pA.y + r1;
        fB.x = pB.x + r2; fB.y = pB.y + r3;
    }
    *apA = fA; *apB = fB;
    if (out16) {
        ushort2 uA, uB;
        uA.x = (ushort)f2bf(fA.x); uA.y = (ushort)f2bf(fA.y);
        uB.x = (ushort)f2bf(fB.x); uB.y = (ushort)f2bf(fB.y);
        *((ushort2*)(out16 + (long)d * 128) + hl) = uA;
        *((ushort2*)(out16 + (long)d * 128 + 64) + hl) = uB;
    }
}

// z0 init: zeros + ptype in col 128
__global__ void init_z0(const float* __restrict__ ptype, float* __restrict__ z0) {
    int i = blockIdx.x * 128 + threadIdx.x;
    if (i < 64 * 129) z0[i] = ((i % 129) == 128) ? ptype[i / 129] : 0.f;
}

// fused JK softmax + pool (64-node chunks, flush on graph boundary)
__global__ __launch_bounds__(128) void pool_jk(
    const float* __restrict__ score, const float* __restrict__ x0,
    const float* __restrict__ x1, const float* __restrict__ x2,
    const int* __restrict__ batch, float* __restrict__ z0, int N)
{
    int c = threadIdx.x;
    int n0 = blockIdx.x * 64;
    if (n0 >= N) return;
    int n1 = min(n0 + 64, N);
    float s = 0.f;
    int g = batch[n0];
    for (int n = n0; n < n1; ++n) {
        int b = batch[n];
        if (b != g) { unsafeAtomicAdd(&z0[g * 129 + c], s); s = 0.f; g = b; }
        float s0 = score[n], s1 = score[N + n], s2 = score[2L * N + n];
        float m = fmaxf(s0, fmaxf(s1, s2));
        float e0 = __expf(s0 - m), e1 = __expf(s1 - m), e2 = __expf(s2 - m);
        float inv = __builtin_amdgcn_rcpf(e0 + e1 + e2);
        long i = (long)n * 128 + c;
        s += (e0 * x0[i] + e1 * x1[i] + e2 * x2[i]) * inv;
    }
    unsafeAtomicAdd(&z0[g * 129 + c], s);
}

__global__ __launch_bounds__(128) void mlp_kernel(
    const float* __restrict__ z0, const float* __restrict__ w1, const float* __restrict__ b1,
    const float* __restrict__ w2, const float* __restrict__ b2,
    const float* __restrict__ w3, const float* __restrict__ b3,
    float* __restrict__ out)
{
    int gidx = blockIdx.x, tid = threadIdx.x;
    __shared__ float zin[129], z1[80], z2[80];
    zin[tid] = z0[gidx * 129 + tid];
    if (tid == 0) zin[128] = z0[gidx * 129 + 128];
    __syncthreads();
    if (tid < 80) {
        float s = b1[tid];
        for (int k = 0; k < 129; ++k) s += zin[k] * w1[k * 80 + tid];
        z1[tid] = lrelu(s, 0.01f);
    }
    __syncthreads();
    if (tid < 80) {
        float s = b2[tid];
        for (int k = 0; k < 80; ++k) s += z1[k] * w2[k * 80 + tid];
        z2[tid] = lrelu(s, 0.01f);
    }
    __syncthreads();
    if (tid < 10) {
        float s = b3[tid];
        for (int k = 0; k < 80; ++k) s += z2[k] * w3[k * 10 + tid];
        out[gidx * 10 + tid] = s;
    }
}

extern "C" void kernel_launch(void* const* d_in, const int* in_sizes, int n_in,
                              void* d_out, int out_size, void* d_ws, size_t ws_size,
                              hipStream_t stream)
{
    (void)n_in; (void)out_size; (void)ws_size;
    const float* x      = (const float*)d_in[0];
    const int*   ei     = (const int*)d_in[1];
    const int*   batch  = (const int*)d_in[2];
    const float* ptype  = (const float*)d_in[3];
    const float* gatW   = (const float*)d_in[4];
    const float* gatAs  = (const float*)d_in[5];
    const float* gatAd  = (const float*)d_in[6];
    const float* gatB   = (const float*)d_in[7];
    const float* w_ih_fw = (const float*)d_in[8];
    const float* w_hh_fw = (const float*)d_in[9];
    const float* b_ih_fw = (const float*)d_in[10];
    const float* b_hh_fw = (const float*)d_in[11];
    const float* w_ih_bw = (const float*)d_in[12];
    const float* w_hh_bw = (const float*)d_in[13];
    const float* b_ih_bw = (const float*)d_in[14];
    const float* b_hh_bw = (const float*)d_in[15];
    const float* jkw    = (const float*)d_in[16];
    const float* fc1w   = (const float*)d_in[18];
    const float* fc1b   = (const float*)d_in[19];
    const float* fc2w   = (const float*)d_in[20];
    const float* fc2b   = (const float*)d_in[21];
    const float* fc3w   = (const float*)d_in[22];
    const float* fc3b   = (const float*)d_in[23];

    const int N = in_sizes[0] / 128;
    const int E = in_sizes[1] / 2;
    const int Et = E / 3;
    const long NC = (long)N * 128;

    float* w = (float*)d_ws;
    float* xp   = w; w += (long)N * 512;    // xp16 (51.2MB) + 4x h bufs (51.2MB)
    float* l1   = w; w += NC;
    float* l2   = w; w += NC;
    float* accb = w; w += NC;               // (unused; layout stability)
    float* outm = w; w += NC;               // GAT: CSR cnt+bucket; LSTM: 2x c bf16
    ushort* xb16 = (ushort*)w; w += 3L * N * 64;   // [3][N][128] bf16 seq
    float* als  = w; w += (long)N * 4;
    float* ald  = w; w += (long)N * 4;
    float* score = w; w += 3L * N;
    ushort* gwt = (ushort*)w; w += 6 * 65536 / 2;   // bf16 GAT weights [6][512][128]
    ushort* lwt = (ushort*)w; w += 4 * 65536 / 2;   // bf16 LSTM weights (permuted)
    float* z0   = w; w += 64 * 129 + 4;

    // CSR aliases the outm region (GAT phase only); LSTM reuses it as 2x cbuf
    int* cnt    = (int*)outm;
    int* bucket = cnt + 3L * N;
    ushort* xp16 = (ushort*)xp;
    ushort* hbase = xp16 + (long)N * 512;   // 4 x [N][128] bf16 (fw0,fw1,bw0,bw1)
    ushort* cbase = (ushort*)outm;          // 2 x [N][128] bf16

    pack_gatw<<<(6 * 65536 + 255) / 256, 256, 0, stream>>>(gatW, gwt);
    pack_lstm<<<(4 * 65536 + 255) / 256, 256, 0, stream>>>(w_ih_fw, w_hh_fw, w_ih_bw, w_hh_bw, lwt);
    pack_x<<<(int)((NC / 4 + 255) / 256), 256, 0, stream>>>(x, xb16, NC);
    hipMemsetAsync(score, 0, sizeof(float) * 3 * N, stream);
    hipMemsetAsync(cnt, 0, sizeof(int) * 3 * N, stream);
    build_csr<<<(E + 255) / 256, 256, 0, stream>>>(ei, ei + E, E, Et, N, cnt, bucket);

    const int RB = (N + 127) / 128;
    const int nwg = RB * 4;

    // ---- GAT layers (A inputs read from bf16 xb16 copies)
    for (int p = 0; p < 2; ++p) {
        const ushort* curA = xb16 + (long)p * N * 128;
        float* dstb = (p == 0) ? l1 : l2;
        ushort* d16 = xb16 + (long)(p + 1) * N * 128;
        for (int t = 0; t < 3; ++t) {
            int pt = p * 3 + t;
            gemm_att<<<nwg, 512, 0, stream>>>(curA, gwt + (long)pt * 65536, xp16,
                                              gatAs + pt * 512, gatAd + pt * 512,
                                              als, ald, N, nwg);
            gat_gather<<<(N + 7) / 8, 256, 0, stream>>>(cnt, bucket, als, ald, xp16,
                                                        gatB + pt * 128, dstb,
                                                        (t == 2) ? d16 : nullptr,
                                                        N, t, t == 0);
        }
    }

    // ---- fused bi-LSTM: both directions per launch, 3 launches
    for (int j = 0; j < 3; ++j) {
        lstm_both<<<dim3(nwg, 2), 512, 0, stream>>>(
            xb16, lwt, hbase, cbase, b_ih_fw, b_hh_fw, b_ih_bw, b_hh_bw,
            jkw, score, N, nwg, j);
    }

    // ---- fused JK softmax + pool, then MLP
    init_z0<<<65, 128, 0, stream>>>(ptype, z0);
    pool_jk<<<(N + 63) / 64, 128, 0, stream>>>(score, x, l1, l2, batch, z0, N);
    mlp_kernel<<<64, 128, 0, stream>>>(z0, fc1w, fc1b, fc2w, fc2b, fc3w, fc3b,
                                       (float*)d_out);
}